// Round 13
// baseline (1847.085 us; speedup 1.0000x reference)
//
#include <hip/hip_runtime.h>

#define DEV __device__ __forceinline__

typedef __bf16 bf16x8 __attribute__((ext_vector_type(8)));
typedef float  f32x4  __attribute__((ext_vector_type(4)));

typedef const __attribute__((address_space(1))) unsigned int* gas_ptr;
typedef       __attribute__((address_space(3))) unsigned int* las_ptr;

DEV unsigned short f2bf(float f) {
  union { __bf16 h; unsigned short u; } c; c.h = (__bf16)f; return c.u;
}

DEV float bf2f(unsigned short u) {
  union { unsigned int i; float f; } c; c.i = (unsigned int)u << 16; return c.f;
}

DEV void gll16(const void* g, void* l) {
  __builtin_amdgcn_global_load_lds((gas_ptr)g, (las_ptr)l, 16, 0, 0);
}

DEV f32x4 mfma16(bf16x8 a, bf16x8 b, f32x4 c) {
  return __builtin_amdgcn_mfma_f32_16x16x32_bf16(a, b, c, 0, 0, 0);
}

// ---------------------------------------------------------------------------
// Transpose + f32->bf16 convert: src [K,N] f32 -> dst [N,K] bf16. grid.z = layer.
__global__ __launch_bounds__(256)
void tcvt_k(const float* __restrict__ src, unsigned short* __restrict__ dst,
            int K, int N)
{
  __shared__ float t[32][33];
  const int tx = threadIdx.x, ty = threadIdx.y;
  const size_t mo = (size_t)blockIdx.z * K * N;
  const int n0 = blockIdx.x * 32, k0 = blockIdx.y * 32;
  const float* s = src + mo;
  unsigned short* d = dst + mo;
#pragma unroll
  for (int i = 0; i < 4; i++)
    t[ty + i*8][tx] = s[(size_t)(k0 + ty + i*8) * N + n0 + tx];
  __syncthreads();
#pragma unroll
  for (int i = 0; i < 4; i++)
    d[(size_t)(n0 + ty + i*8) * K + k0 + tx] = f2bf(t[tx][ty + i*8]);
}

// ---------------------------------------------------------------------------
// Shared LN tail
DEV void ln_tail(float4 s, const float* __restrict__ g,
                 const float* __restrict__ bta,
                 unsigned short* __restrict__ hrow, int t, float* red)
{
  float sm  = s.x + s.y + s.z + s.w;
  float sq = s.x*s.x + s.y*s.y + s.z*s.z + s.w*s.w;
#pragma unroll
  for (int mk = 32; mk >= 1; mk >>= 1) {
    sm += __shfl_xor(sm, mk);
    sq += __shfl_xor(sq, mk);
  }
  const int wv = t >> 6;
  if ((t & 63) == 0) { red[wv] = sm; red[4 + wv] = sq; }
  __syncthreads();
  sm = red[0] + red[1] + red[2] + red[3];
  sq = red[4] + red[5] + red[6] + red[7];
  const float mu = sm * (1.f/1024.f);
  const float rs = rsqrtf(sq * (1.f/1024.f) - mu*mu + 1e-5f);
  const float4 gv = ((const float4*)g)[t];
  const float4 bv = ((const float4*)bta)[t];
  ushort4 o;
  o.x = f2bf((s.x - mu) * rs * gv.x + bv.x);
  o.y = f2bf((s.y - mu) * rs * gv.y + bv.y);
  o.z = f2bf((s.z - mu) * rs * gv.z + bv.z);
  o.w = f2bf((s.w - mu) * rs * gv.w + bv.w);
  ((ushort4*)hrow)[t] = o;
}

// ---------------------------------------------------------------------------
// Embedding + LN1(layer0)
__global__ __launch_bounds__(256)
void embed_ln_k(const int* __restrict__ toks, const float* __restrict__ te,
                const float* __restrict__ pe, const float* __restrict__ g,
                const float* __restrict__ bta,
                float* __restrict__ x, unsigned short* __restrict__ h)
{
  __shared__ float red[8];
  const int row = blockIdx.x, t = threadIdx.x;
  const int tok = toks[row], s = row & 1023;
  float4 a = ((const float4*)(te + (size_t)tok * 1024))[t];
  float4 p = ((const float4*)(pe + (size_t)s   * 1024))[t];
  float4 v; v.x = a.x+p.x; v.y = a.y+p.y; v.z = a.z+p.z; v.w = a.w+p.w;
  ((float4*)(x + (size_t)row * 1024))[t] = v;
  ln_tail(v, g, bta, h + (size_t)row * 1024, t, red);
}

// ---------------------------------------------------------------------------
// Fused split-K reduce (4 bf16 partials) + residual + bias + LayerNorm.
__global__ __launch_bounds__(256)
void redln_k(const unsigned short* __restrict__ part,
             const float* __restrict__ bias,
             const float* __restrict__ g, const float* __restrict__ bta,
             float* __restrict__ x, unsigned short* __restrict__ h)
{
  __shared__ float red[8];
  const int row = blockIdx.x, t = threadIdx.x;
  const size_t pbase = (size_t)row * 1024 + t * 4;
  float a0 = 0.f, a1 = 0.f, a2 = 0.f, a3 = 0.f;
#pragma unroll
  for (int kz = 0; kz < 4; kz++) {
    ushort4 u = *(const ushort4*)&part[(size_t)kz * 4194304 + pbase];
    a0 += bf2f(u.x); a1 += bf2f(u.y); a2 += bf2f(u.z); a3 += bf2f(u.w);
  }
  float4 xv = ((const float4*)(x + (size_t)row * 1024))[t];
  float4 bv = ((const float4*)bias)[t];
  float4 s;
  s.x = xv.x + a0 + bv.x; s.y = xv.y + a1 + bv.y;
  s.z = xv.z + a2 + bv.z; s.w = xv.w + a3 + bv.w;
  ((float4*)(x + (size_t)row * 1024))[t] = s;
  ln_tail(s, g, bta, h + (size_t)row * 1024, t, red);
}

// ---------------------------------------------------------------------------
// bf16 GEMM, m97 structure + counted-vmcnt double-buffer (logits path only).
// EPI: 4 = split-K f32 partial
template<int EPI>
__global__ __launch_bounds__(256)
void gemm_k(const unsigned short* __restrict__ A,
            const unsigned short* __restrict__ B0,
            int K, int N, int Kc, float* __restrict__ part)
{
  __shared__ __align__(16) unsigned short As[2][128 * 32];
  __shared__ __align__(16) unsigned short Bs[2][128 * 32];
  const int tid = threadIdx.x;
  const int wave = tid >> 6, lane = tid & 63;
  const int wm = wave >> 1, wn = wave & 1;
  const int m0 = blockIdx.x * 128, n0 = blockIdx.y * 128;
  const int r16 = lane & 15, r4 = lane >> 4;

  const int koff = blockIdx.z * Kc;

  const unsigned short* ga = A  + (size_t)(m0 + (tid >> 2)) * K + koff + (tid & 3) * 8;
  const unsigned short* gb = B0 + (size_t)(n0 + (tid >> 2)) * K + koff + (tid & 3) * 8;
  const size_t rstep = (size_t)64 * K;
  const int lo = wave * 512;

  auto STAGE = [&](int slot, int tt) {
    const unsigned short* gaa = ga + tt * 32;
    const unsigned short* gbb = gb + tt * 32;
    gll16(gaa,         &As[slot][lo]);
    gll16(gaa + rstep, &As[slot][lo + 2048]);
    gll16(gbb,         &Bs[slot][lo]);
    gll16(gbb + rstep, &Bs[slot][lo + 2048]);
  };

  f32x4 acc[4][4] = {};
  const int NT = Kc >> 5;

  STAGE(0, 0);
  if (NT > 1) STAGE(1, 1);

  for (int t = 0; t < NT; t++) {
    if (t + 1 < NT) asm volatile("s_waitcnt vmcnt(4)" ::: "memory");
    else            asm volatile("s_waitcnt vmcnt(0)" ::: "memory");
    __builtin_amdgcn_sched_barrier(0);
    __builtin_amdgcn_s_barrier();
    __builtin_amdgcn_sched_barrier(0);

    const int slot = t & 1;
    bf16x8 av[4], bv[4];
#pragma unroll
    for (int mf = 0; mf < 4; mf++)
      av[mf] = *(const bf16x8*)&As[slot][(wm*64 + mf*16 + r16) * 32 + r4 * 8];
#pragma unroll
    for (int nf = 0; nf < 4; nf++)
      bv[nf] = *(const bf16x8*)&Bs[slot][(wn*64 + nf*16 + r16) * 32 + r4 * 8];
    asm volatile("s_waitcnt lgkmcnt(0)" ::: "memory");
    __builtin_amdgcn_sched_barrier(0);
    __builtin_amdgcn_s_barrier();
    __builtin_amdgcn_sched_barrier(0);

    if (t + 2 < NT) STAGE(slot, t + 2);

#pragma unroll
    for (int mf = 0; mf < 4; mf++)
#pragma unroll
      for (int nf = 0; nf < 4; nf++)
        acc[mf][nf] = mfma16(av[mf], bv[nf], acc[mf][nf]);
    __builtin_amdgcn_sched_barrier(0);
  }

  const int row0 = m0 + wm * 64, col0 = n0 + wn * 64;
  float* po = part + (size_t)blockIdx.z * ((size_t)gridDim.x * 128 * N);
#pragma unroll
  for (int mf = 0; mf < 4; mf++)
#pragma unroll
    for (int nf = 0; nf < 4; nf++)
#pragma unroll
      for (int jj = 0; jj < 4; jj++) {
        const int r = row0 + mf*16 + r4*4 + jj;
        const int c = col0 + nf*16 + r16;
        po[(size_t)r * N + c] = acc[mf][nf][jj];
      }
}

// ---------------------------------------------------------------------------
// 256x256 8-phase GEMM (T3+T4+T5), BK=64, 512 thr / 8 waves. (R12, passing.)
// EPI: 0 = QKV scatter (z selects Wq/Wk/Wv; q scaled 0.125; v transposed)
//      2 = relu(acc+bias)->bf16, 5 = bf16 split-K partial (o0 + z*4194304)
template<int EPI>
__global__ __launch_bounds__(512, 2)
void gemm8_k(const unsigned short* __restrict__ A,
             const unsigned short* __restrict__ B0,
             const unsigned short* __restrict__ B1,
             const unsigned short* __restrict__ B2,
             const float* __restrict__ bias,
             unsigned short* __restrict__ o0,
             unsigned short* __restrict__ o1,
             unsigned short* __restrict__ o2,
             int K, int N, int Kc)
{
  __shared__ __align__(16) unsigned short LA[2][2][8192];
  __shared__ __align__(16) unsigned short LB[2][2][8192];
  const int tid = threadIdx.x;
  const int wave = tid >> 6, lane = tid & 63;
  const int wm = wave >> 2, wn = wave & 3;
  const int r16 = lane & 15, r4 = lane >> 4;
  const int m0 = blockIdx.x * 256, n0 = blockIdx.y * 256;
  const int koff = (EPI == 5) ? blockIdx.z * Kc : 0;
  const int NT = Kc >> 6;

  const unsigned short* Bt = B0;
  if (EPI == 0) Bt = (blockIdx.z == 0) ? B0 : (blockIdx.z == 1) ? B1 : B2;

  const unsigned short* As0 = A  + (size_t)m0 * K + koff;
  const unsigned short* As1 = A  + (size_t)(m0 + 128) * K + koff;
  const unsigned short* Bs0 = Bt + (size_t)n0 * K + koff;
  const unsigned short* Bs1 = Bt + (size_t)(n0 + 128) * K + koff;

  auto STAGEH = [&](unsigned short* lds, const unsigned short* gsrc) {
    const int c0 = tid, r0 = c0 >> 3;
    gll16(gsrc + (size_t)r0 * K + ((c0 & 7) ^ (r0 & 7)) * 8, lds + c0 * 8);
    const int c1 = 512 + tid, r1 = c1 >> 3;
    gll16(gsrc + (size_t)r1 * K + ((c1 & 7) ^ (r1 & 7)) * 8, lds + c1 * 8);
  };

  f32x4 acc[8][4] = {};
  bf16x8 avx[4][2], bvx[2][2][2];

  STAGEH(&LB[0][0][0], Bs0);
  STAGEH(&LB[0][1][0], Bs1);
  STAGEH(&LA[0][0][0], As0);
  STAGEH(&LA[0][1][0], As1);
  if (NT > 1) {
    STAGEH(&LB[1][0][0], Bs0 + 64);
    STAGEH(&LB[1][1][0], Bs1 + 64);
  }

  for (int t = 0; t < NT; ++t) {
    const int slot = t & 1;
    if (t + 1 < NT) asm volatile("s_waitcnt vmcnt(4)" ::: "memory");
    else            asm volatile("s_waitcnt vmcnt(0)" ::: "memory");
    __builtin_amdgcn_sched_barrier(0);
    __builtin_amdgcn_s_barrier();
    __builtin_amdgcn_sched_barrier(0);

    // ---- p1: (qr0, qc0)
#pragma unroll
    for (int mfq = 0; mfq < 4; mfq++)
#pragma unroll
      for (int kk = 0; kk < 2; kk++)
        avx[mfq][kk] = *(const bf16x8*)&LA[slot][wm][
            (mfq*16 + r16) * 64 + (((kk*4 + r4) ^ (r16 & 7)) * 8)];
#pragma unroll
    for (int nfq = 0; nfq < 2; nfq++)
#pragma unroll
      for (int kk = 0; kk < 2; kk++)
        bvx[0][nfq][kk] = *(const bf16x8*)&LB[slot][wn >> 1][
            ((wn & 1)*64 + nfq*16 + r16) * 64 + (((kk*4 + r4) ^ (r16 & 7)) * 8)];
    if (t + 1 < NT) STAGEH(&LA[slot ^ 1][0][0], As0 + (t + 1) * 64);
    asm volatile("s_waitcnt lgkmcnt(0)" ::: "memory");
    __builtin_amdgcn_sched_barrier(0);
    __builtin_amdgcn_s_setprio(1);
#pragma unroll
    for (int mfq = 0; mfq < 4; mfq++)
#pragma unroll
      for (int nfq = 0; nfq < 2; nfq++)
#pragma unroll
        for (int kk = 0; kk < 2; kk++)
          acc[mfq][nfq] = mfma16(avx[mfq][kk], bvx[0][nfq][kk], acc[mfq][nfq]);
    __builtin_amdgcn_s_setprio(0);

    // ---- p2: (qr0, qc1)
#pragma unroll
    for (int nfq = 0; nfq < 2; nfq++)
#pragma unroll
      for (int kk = 0; kk < 2; kk++)
        bvx[1][nfq][kk] = *(const bf16x8*)&LB[slot][wn >> 1][
            ((wn & 1)*64 + 32 + nfq*16 + r16) * 64 + (((kk*4 + r4) ^ (r16 & 7)) * 8)];
    if (t + 1 < NT) STAGEH(&LA[slot ^ 1][1][0], As1 + (t + 1) * 64);
    asm volatile("s_waitcnt lgkmcnt(0)" ::: "memory");
    __builtin_amdgcn_sched_barrier(0);
    __builtin_amdgcn_s_setprio(1);
#pragma unroll
    for (int mfq = 0; mfq < 4; mfq++)
#pragma unroll
      for (int nfq = 0; nfq < 2; nfq++)
#pragma unroll
        for (int kk = 0; kk < 2; kk++)
          acc[mfq][2 + nfq] = mfma16(avx[mfq][kk], bvx[1][nfq][kk], acc[mfq][2 + nfq]);
    __builtin_amdgcn_s_setprio(0);

    __builtin_amdgcn_sched_barrier(0);
    __builtin_amdgcn_s_barrier();
    __builtin_amdgcn_sched_barrier(0);

    // ---- p3: (qr1, qc0)
#pragma unroll
    for (int mfq = 0; mfq < 4; mfq++)
#pragma unroll
      for (int kk = 0; kk < 2; kk++)
        avx[mfq][kk] = *(const bf16x8*)&LA[slot][wm][
            (64 + mfq*16 + r16) * 64 + (((kk*4 + r4) ^ (r16 & 7)) * 8)];
    if (t + 2 < NT) STAGEH(&LB[slot][0][0], Bs0 + (t + 2) * 64);
    asm volatile("s_waitcnt lgkmcnt(0)" ::: "memory");
    __builtin_amdgcn_sched_barrier(0);
    __builtin_amdgcn_s_setprio(1);
#pragma unroll
    for (int mfq = 0; mfq < 4; mfq++)
#pragma unroll
      for (int nfq = 0; nfq < 2; nfq++)
#pragma unroll
        for (int kk = 0; kk < 2; kk++)
          acc[4 + mfq][nfq] = mfma16(avx[mfq][kk], bvx[0][nfq][kk], acc[4 + mfq][nfq]);
    __builtin_amdgcn_s_setprio(0);

    // ---- p4: (qr1, qc1)
    if (t + 2 < NT) STAGEH(&LB[slot][1][0], Bs1 + (t + 2) * 64);
    __builtin_amdgcn_s_setprio(1);
#pragma unroll
    for (int mfq = 0; mfq < 4; mfq++)
#pragma unroll
      for (int nfq = 0; nfq < 2; nfq++)
#pragma unroll
        for (int kk = 0; kk < 2; kk++)
          acc[4 + mfq][2 + nfq] = mfma16(avx[mfq][kk], bvx[1][nfq][kk], acc[4 + mfq][2 + nfq]);
    __builtin_amdgcn_s_setprio(0);
    __builtin_amdgcn_sched_barrier(0);
  }

  // epilogue
  const int row0 = m0 + wm * 128, col0 = n0 + wn * 64;
  unsigned short* po16 = o0;
  if (EPI == 5) po16 = o0 + (size_t)blockIdx.z * 4194304;
#pragma unroll
  for (int mf = 0; mf < 8; mf++) {
#pragma unroll
    for (int nf = 0; nf < 4; nf++) {
#pragma unroll
      for (int jj = 0; jj < 4; jj++) {
        const int r = row0 + mf*16 + r4*4 + jj;
        const int c = col0 + nf*16 + r16;
        const float v = acc[mf][nf][jj];
        if (EPI == 0) {
          const int z = blockIdx.z;
          const int b_ = r >> 10, s_ = r & 1023;
          const int hh = c >> 6, e = c & 63;
          if (z == 0)
            o0[((size_t)(b_*16 + hh) * 1024 + s_) * 64 + e] = f2bf(v * 0.125f);
          else if (z == 1)
            o1[((size_t)(b_*16 + hh) * 1024 + s_) * 64 + e] = f2bf(v);
          else
            o2[((size_t)(b_*16 + hh) * 64 + e) * 1024 + s_] = f2bf(v);
        } else if (EPI == 2) {
          const float t2 = v + bias[c];
          po16[(size_t)r * N + c] = f2bf(t2 > 0.f ? t2 : 0.f);
        } else {
          po16[(size_t)r * N + c] = f2bf(v);
        }
      }
    }
  }
}

// ---------------------------------------------------------------------------
// Split-K reduce (f32 partials, logits path): outw = sum + bias.
__global__ __launch_bounds__(256)
void red_k(const float* __restrict__ part, const float* __restrict__ bias,
           float* __restrict__ outw, int n4, int nm4, int KZ)
{
  const float4* p4 = (const float4*)part;
  const float4* b4 = (const float4*)bias;
  for (size_t i = (size_t)blockIdx.x * 256 + threadIdx.x; i < (size_t)n4;
       i += (size_t)gridDim.x * 256) {
    float4 s = p4[i];
    for (int kz = 1; kz < KZ; kz++) {
      float4 t = p4[i + (size_t)kz * n4];
      s.x += t.x; s.y += t.y; s.z += t.z; s.w += t.w;
    }
    float4 bv = b4[i & nm4];
    s.x += bv.x; s.y += bv.y; s.z += bv.z; s.w += bv.w;
    ((float4*)outw)[i] = s;
  }
}

// ---------------------------------------------------------------------------
// Flash attention v2: 512 thr / 8 waves, QBLK=128 (wave w owns rows
// q0+w*16..+15), KVBLK=64, counted-vmcnt (2 loads/tile/wave -> vmcnt(2)),
// fixed-shift softmax, T2 swizzle, wave-uniform skip of fully-masked tiles
// (skipped waves still stage + hit both barriers -> sync audit unchanged).
// LDS 50KB -> 3 blocks/CU (24 waves/CU). Grid 512 flat, XCD decode.
__global__ __launch_bounds__(512)
void attn_k(const unsigned short* __restrict__ qb,
            const unsigned short* __restrict__ kb,
            const unsigned short* __restrict__ vtb,
            unsigned short* __restrict__ att)
{
  __shared__ __align__(16) unsigned short Ks[2][64 * 64];
  __shared__ __align__(16) unsigned short Vs[2][64 * 64];
  __shared__ __align__(16) unsigned short Ps[128 * 72];
  const int flat = blockIdx.x;
  const int job  = (flat & 7) * 64 + (flat >> 3);   // XCD-contiguous decode
  const int qt   = 7 - (job & 7);                   // longest-first in chunk
  const int h    = (job >> 3) & 15;
  const int b    = job >> 7;
  const int tid = threadIdx.x, wave = tid >> 6, lane = tid & 63;
  const int r16 = lane & 15, r4 = lane >> 4;
  const int q0 = qt * 128;
  const size_t bh = (size_t)(b * 16 + h);
  const unsigned short* qbh = qb  + bh * 1024 * 64;
  const unsigned short* kbh = kb  + bh * 1024 * 64;
  const unsigned short* vbh = vtb + bh * 64 * 1024;

  // stage: 512 thr x 16B = one full 64x64 bf16 tile per array per call.
  // thread tid -> row tid>>3, chunk tid&7; source chunk ^(row&7); LDS linear.
  const int srow = tid >> 3;
  const int swz  = ((tid & 7) ^ (srow & 7)) * 8;
  auto STAGE = [&](int slot, int tt) {
    const int kv0 = tt * 64;
    gll16(kbh + (size_t)(kv0 + srow) * 64 + swz,   &Ks[slot][tid * 8]);
    gll16(vbh + (size_t)srow * 1024 + kv0 + swz,   &Vs[slot][tid * 8]);
  };

  const int wrow0 = q0 + wave * 16;   // wave's first q row
  bf16x8 qf[2];
#pragma unroll
  for (int kc = 0; kc < 2; kc++)
    qf[kc] = *(const bf16x8*)&qbh[(size_t)(wrow0 + r16) * 64 + kc*32 + r4*8];

  f32x4 oacc[4] = {};
  float l_i[4] = {0.f, 0.f, 0.f, 0.f};

  const int nt = 2 * qt + 2;   // kv tiles 0..2qt+1 cover kv <= q0+127

  STAGE(0, 0);
  if (nt > 1) STAGE(1, 1);

  for (int t = 0; t < nt; t++) {
    if (t + 1 < nt) asm volatile("s_waitcnt vmcnt(2)" ::: "memory");
    else            asm volatile("s_waitcnt vmcnt(0)" ::: "memory");
    __builtin_amdgcn_sched_barrier(0);
    __builtin_amdgcn_s_barrier();      // all waves' staging of slot landed
    __builtin_amdgcn_sched_barrier(0);

    const int slot = t & 1;
    const int kv0 = t * 64;
    const bool active = (kv0 <= wrow0 + 15);   // wave-uniform

    bf16x8 kf[2][4], vf[2][4];
    if (active) {
#pragma unroll
      for (int kc = 0; kc < 2; kc++)
#pragma unroll
        for (int nf = 0; nf < 4; nf++) {
          kf[kc][nf] = *(const bf16x8*)&Ks[slot][(nf*16 + r16) * 64 +
                                                (((kc*4 + r4) ^ (r16 & 7)) * 8)];
          vf[kc][nf] = *(const bf16x8*)&Vs[slot][(nf*16 + r16) * 64 +
                                                (((kc*4 + r4) ^ (r16 & 7)) * 8)];
        }
    }
    asm volatile("s_waitcnt lgkmcnt(0)" ::: "memory");
    __builtin_amdgcn_sched_barrier(0);
    __builtin_amdgcn_s_barrier();      // all waves done reading slot
    __builtin_amdgcn_sched_barrier(0);

    if (t + 2 < nt) STAGE(slot, t + 2);

    if (active) {
      f32x4 sacc[4] = {};
#pragma unroll
      for (int kc = 0; kc < 2; kc++)
#pragma unroll
        for (int nf = 0; nf < 4; nf++)
          sacc[nf] = mfma16(qf[kc], kf[kc][nf], sacc[nf]);

      const bool needmask = (kv0 + 63 > wrow0);   // wave-uniform
#pragma unroll
      for (int jj = 0; jj < 4; jj++) {
        float vv[4];
#pragma unroll
        for (int nf = 0; nf < 4; nf++) vv[nf] = sacc[nf][jj];
        if (needmask) {
          const int qrow = wrow0 + r4*4 + jj;
#pragma unroll
          for (int nf = 0; nf < 4; nf++)
            if (kv0 + nf*16 + r16 > qrow) vv[nf] = -1e30f;
        }
        float p0 = __expf(vv[0]), p1 = __expf(vv[1]);
        float p2 = __expf(vv[2]), p3 = __expf(vv[3]);
        l_i[jj] += (p0 + p1) + (p2 + p3);
        const int prow = (wave*16 + r4*4 + jj) * 72;
        Ps[prow + r16     ] = f2bf(p0);
        Ps[prow + 16 + r16] = f2bf(p1);
        Ps[prow + 32 + r16] = f2bf(p2);
        Ps[prow + 48 + r16] = f2bf(p3);
      }

#pragma unroll
      for (int kc = 0; kc < 2; kc++) {
        bf16x8 pf = *(const bf16x8*)&Ps[(wave*16 + r16) * 72 + kc*32 + r4*8];
#pragma unroll
        for (int nh = 0; nh < 4; nh++)
          oacc[nh] = mfma16(pf, vf[kc][nh], oacc[nh]);
      }
    }
    __builtin_amdgcn_sched_barrier(0);
  }

#pragma unroll
  for (int jj = 0; jj < 4; jj++)
#pragma unroll
    for (int mk = 8; mk >= 1; mk >>= 1) l_i[jj] += __shfl_xor(l_i[jj], mk);

#pragma unroll
  for (int nh = 0; nh < 4; nh++) {
#pragma unroll
    for (int jj = 0; jj < 4; jj++) {
      const int row = wrow0 + r4*4 + jj;
      const int col = nh*16 + r16;
      const float o = oacc[nh][jj] / l_i[jj];
      att[(size_t)(b * 1024 + row) * 1024 + h*64 + col] = f2bf(o);
    }
  }
}

// ---------------------------------------------------------------------------
extern "C" void kernel_launch(void* const* d_in, const int* in_sizes, int n_in,
                              void* d_out, int out_size, void* d_ws, size_t ws_size,
                              hipStream_t stream)
{
  const int*   toks    = (const int*)  d_in[0];
  const float* tok_emb = (const float*)d_in[1];
  const float* pos_emb = (const float*)d_in[2];
  const float* Wq      = (const float*)d_in[3];
  const float* Wk      = (const float*)d_in[4];
  const float* Wv      = (const float*)d_in[5];
  const float* Wo      = (const float*)d_in[6];
  const float* bo      = (const float*)d_in[7];
  const float* ln1_g   = (const float*)d_in[8];
  const float* ln1_b   = (const float*)d_in[9];
  const float* ln2_g   = (const float*)d_in[10];
  const float* ln2_b   = (const float*)d_in[11];
  const float* W1      = (const float*)d_in[12];
  const float* b1      = (const float*)d_in[13];
  const float* W2      = (const float*)d_in[14];
  const float* b2      = (const float*)d_in[15];
  const float* lnf_g   = (const float*)d_in[16];
  const float* lnf_b   = (const float*)d_in[17];
  const float* Wout    = (const float*)d_in[18];
  const float* bout    = (const float*)d_in[19];
  float* out = (float*)d_out;

  char* w = (char*)d_ws;
  size_t off = 0;
  auto alloc = [&](size_t bytes) -> void* {
    void* p = w + off; off += (bytes + 255) & ~(size_t)255; return p;
  };
  unsigned short* wqT   = (unsigned short*)alloc(8ull*1024*1024*2);
  unsigned short* wkT   = (unsigned short*)alloc(8ull*1024*1024*2);
  unsigned short* wvT   = (unsigned short*)alloc(8ull*1024*1024*2);
  unsigned short* woT   = (unsigned short*)alloc(8ull*1024*1024*2);
  unsigned short* w1T   = (unsigned short*)alloc(8ull*1024*4096*2);
  unsigned short* w2T   = (unsigned short*)alloc(8ull*4096*1024*2);
  unsigned short* woutT = (unsigned short*)alloc(256ull*1024*2);
  float*          x     = (float*)         alloc(4096ull*1024*4);
  unsigned short* hbuf  = (unsigned short*)alloc(4096ull*1024*2);
  unsigned short* qbuf  = (unsigned short*)alloc(64ull*1024*64*2);
  unsigned short* kbuf  = (unsigned short*)alloc(64ull*1024*64*2);
  unsigned short* vtb   = (unsigned short*)alloc(64ull*1024*64*2);
  unsigned short* att   = (unsigned short*)alloc(4096ull*1024*2);
  unsigned short* ff    = (unsigned short*)alloc(4096ull*4096*2);
  unsigned short* part16= (unsigned short*)alloc(4ull*4194304*2);   // bf16 split-K partials
  float*          part  = (float*)         alloc(8ull*1048576*4);   // f32 partials (logits)
  (void)ws_size; (void)in_sizes; (void)n_in; (void)out_size;

  dim3 tb(32, 8);
  tcvt_k<<<dim3(32, 32, 8),  tb, 0, stream>>>(Wq,   wqT,   1024, 1024);
  tcvt_k<<<dim3(32, 32, 8),  tb, 0, stream>>>(Wk,   wkT,   1024, 1024);
  tcvt_k<<<dim3(32, 32, 8),  tb, 0, stream>>>(Wv,   wvT,   1024, 1024);
  tcvt_k<<<dim3(32, 32, 8),  tb, 0, stream>>>(Wo,   woT,   1024, 1024);
  tcvt_k<<<dim3(128, 32, 8), tb, 0, stream>>>(W1,   w1T,   1024, 4096);
  tcvt_k<<<dim3(32, 128, 8), tb, 0, stream>>>(W2,   w2T,   4096, 1024);
  tcvt_k<<<dim3(8, 32, 1),   tb, 0, stream>>>(Wout, woutT, 1024, 256);

  // embed + layer-0 LN1 fused
  embed_ln_k<<<4096, 256, 0, stream>>>(toks, tok_emb, pos_emb,
                                       ln1_g, ln1_b, x, hbuf);

  for (int l = 0; l < 8; l++) {
    // QKV: 256^2 8-phase, z selects Wq/Wk/Wv, scatter epilogue
    gemm8_k<0><<<dim3(16, 4, 3), 512, 0, stream>>>(hbuf,
        wqT + (size_t)l*1048576, wkT + (size_t)l*1048576, wvT + (size_t)l*1048576,
        nullptr, qbuf, kbuf, vtb, 1024, 1024, 1024);
    attn_k<<<512, 512, 0, stream>>>(qbuf, kbuf, vtb, att);
    // Wo: 256^2 8-phase split-K x4 (Kc=256) -> bf16 partials, fused reduce+LN2
    gemm8_k<5><<<dim3(16, 4, 4), 512, 0, stream>>>(att,
        woT + (size_t)l*1048576, nullptr, nullptr,
        nullptr, part16, nullptr, nullptr, 1024, 1024, 256);
    redln_k<<<4096, 256, 0, stream>>>(part16, bo + l*1024,
        ln2_g + l*1024, ln2_b + l*1024, x, hbuf);
    // FFN1: 256^2 8-phase, relu -> bf16 ff
    gemm8_k<2><<<dim3(16, 16), 512, 0, stream>>>(hbuf,
        w1T + (size_t)l*4194304, nullptr, nullptr,
        b1 + l*4096, ff, nullptr, nullptr, 1024, 4096, 1024);
    // FFN2: 256^2 8-phase split-K x4 (Kc=1024) -> bf16 partials
    gemm8_k<5><<<dim3(16, 4, 4), 512, 0, stream>>>(ff,
        w2T + (size_t)l*4194304, nullptr, nullptr,
        nullptr, part16, nullptr, nullptr, 4096, 1024, 1024);
    if (l < 7)
      redln_k<<<4096, 256, 0, stream>>>(part16, b2 + l*1024,
          ln1_g + (l+1)*1024, ln1_b + (l+1)*1024, x, hbuf);
    else
      redln_k<<<4096, 256, 0, stream>>>(part16, b2 + l*1024,
          lnf_g, lnf_b, x, hbuf);
  }

  // logits: split-K x8 (Kc=128, f32 partials), then bias-reduce into out
  gemm_k<4><<<dim3(32, 2, 8), 256, 0, stream>>>(hbuf, woutT,
      1024, 256, 128, part);
  red_k<<<1024, 256, 0, stream>>>(part, bout, out, 262144, 63, 8);
}

// Round 14
// 1815.958 us; speedup vs baseline: 1.0171x; 1.0171x over previous
//
#include <hip/hip_runtime.h>

#define DEV __device__ __forceinline__

typedef __bf16 bf16x8 __attribute__((ext_vector_type(8)));
typedef float  f32x4  __attribute__((ext_vector_type(4)));

typedef const __attribute__((address_space(1))) unsigned int* gas_ptr;
typedef       __attribute__((address_space(3))) unsigned int* las_ptr;

DEV unsigned short f2bf(float f) {
  union { __bf16 h; unsigned short u; } c; c.h = (__bf16)f; return c.u;
}

DEV float bf2f(unsigned short u) {
  union { unsigned int i; float f; } c; c.i = (unsigned int)u << 16; return c.f;
}

DEV void gll16(const void* g, void* l) {
  __builtin_amdgcn_global_load_lds((gas_ptr)g, (las_ptr)l, 16, 0, 0);
}

DEV f32x4 mfma16(bf16x8 a, bf16x8 b, f32x4 c) {
  return __builtin_amdgcn_mfma_f32_16x16x32_bf16(a, b, c, 0, 0, 0);
}

// ---------------------------------------------------------------------------
// Transpose + f32->bf16 convert: src [K,N] f32 -> dst [N,K] bf16. grid.z = layer.
__global__ __launch_bounds__(256)
void tcvt_k(const float* __restrict__ src, unsigned short* __restrict__ dst,
            int K, int N)
{
  __shared__ float t[32][33];
  const int tx = threadIdx.x, ty = threadIdx.y;
  const size_t mo = (size_t)blockIdx.z * K * N;
  const int n0 = blockIdx.x * 32, k0 = blockIdx.y * 32;
  const float* s = src + mo;
  unsigned short* d = dst + mo;
#pragma unroll
  for (int i = 0; i < 4; i++)
    t[ty + i*8][tx] = s[(size_t)(k0 + ty + i*8) * N + n0 + tx];
  __syncthreads();
#pragma unroll
  for (int i = 0; i < 4; i++)
    d[(size_t)(n0 + ty + i*8) * K + k0 + tx] = f2bf(t[tx][ty + i*8]);
}

// ---------------------------------------------------------------------------
// Shared LN tail
DEV void ln_tail(float4 s, const float* __restrict__ g,
                 const float* __restrict__ bta,
                 unsigned short* __restrict__ hrow, int t, float* red)
{
  float sm  = s.x + s.y + s.z + s.w;
  float sq = s.x*s.x + s.y*s.y + s.z*s.z + s.w*s.w;
#pragma unroll
  for (int mk = 32; mk >= 1; mk >>= 1) {
    sm += __shfl_xor(sm, mk);
    sq += __shfl_xor(sq, mk);
  }
  const int wv = t >> 6;
  if ((t & 63) == 0) { red[wv] = sm; red[4 + wv] = sq; }
  __syncthreads();
  sm = red[0] + red[1] + red[2] + red[3];
  sq = red[4] + red[5] + red[6] + red[7];
  const float mu = sm * (1.f/1024.f);
  const float rs = rsqrtf(sq * (1.f/1024.f) - mu*mu + 1e-5f);
  const float4 gv = ((const float4*)g)[t];
  const float4 bv = ((const float4*)bta)[t];
  ushort4 o;
  o.x = f2bf((s.x - mu) * rs * gv.x + bv.x);
  o.y = f2bf((s.y - mu) * rs * gv.y + bv.y);
  o.z = f2bf((s.z - mu) * rs * gv.z + bv.z);
  o.w = f2bf((s.w - mu) * rs * gv.w + bv.w);
  ((ushort4*)hrow)[t] = o;
}

// ---------------------------------------------------------------------------
// Embedding + LN1(layer0)
__global__ __launch_bounds__(256)
void embed_ln_k(const int* __restrict__ toks, const float* __restrict__ te,
                const float* __restrict__ pe, const float* __restrict__ g,
                const float* __restrict__ bta,
                float* __restrict__ x, unsigned short* __restrict__ h)
{
  __shared__ float red[8];
  const int row = blockIdx.x, t = threadIdx.x;
  const int tok = toks[row], s = row & 1023;
  float4 a = ((const float4*)(te + (size_t)tok * 1024))[t];
  float4 p = ((const float4*)(pe + (size_t)s   * 1024))[t];
  float4 v; v.x = a.x+p.x; v.y = a.y+p.y; v.z = a.z+p.z; v.w = a.w+p.w;
  ((float4*)(x + (size_t)row * 1024))[t] = v;
  ln_tail(v, g, bta, h + (size_t)row * 1024, t, red);
}

// ---------------------------------------------------------------------------
// Fused split-K reduce (4 bf16 partials) + residual + bias + LayerNorm.
__global__ __launch_bounds__(256)
void redln_k(const unsigned short* __restrict__ part,
             const float* __restrict__ bias,
             const float* __restrict__ g, const float* __restrict__ bta,
             float* __restrict__ x, unsigned short* __restrict__ h)
{
  __shared__ float red[8];
  const int row = blockIdx.x, t = threadIdx.x;
  const size_t pbase = (size_t)row * 1024 + t * 4;
  float a0 = 0.f, a1 = 0.f, a2 = 0.f, a3 = 0.f;
#pragma unroll
  for (int kz = 0; kz < 4; kz++) {
    ushort4 u = *(const ushort4*)&part[(size_t)kz * 4194304 + pbase];
    a0 += bf2f(u.x); a1 += bf2f(u.y); a2 += bf2f(u.z); a3 += bf2f(u.w);
  }
  float4 xv = ((const float4*)(x + (size_t)row * 1024))[t];
  float4 bv = ((const float4*)bias)[t];
  float4 s;
  s.x = xv.x + a0 + bv.x; s.y = xv.y + a1 + bv.y;
  s.z = xv.z + a2 + bv.z; s.w = xv.w + a3 + bv.w;
  ((float4*)(x + (size_t)row * 1024))[t] = s;
  ln_tail(s, g, bta, h + (size_t)row * 1024, t, red);
}

// ---------------------------------------------------------------------------
// bf16 GEMM, m97 structure + counted-vmcnt double-buffer. (R8, passing.)
// EPI: 4 = split-K f32 partial  5 = split-K bf16 partial (o0 + z*4194304)
template<int EPI>
__global__ __launch_bounds__(256)
void gemm_k(const unsigned short* __restrict__ A,
            const unsigned short* __restrict__ B0,
            unsigned short* __restrict__ o0,
            int K, int N, int Kc, float* __restrict__ part)
{
  __shared__ __align__(16) unsigned short As[2][128 * 32];
  __shared__ __align__(16) unsigned short Bs[2][128 * 32];
  const int tid = threadIdx.x;
  const int wave = tid >> 6, lane = tid & 63;
  const int wm = wave >> 1, wn = wave & 1;
  const int m0 = blockIdx.x * 128, n0 = blockIdx.y * 128;
  const int r16 = lane & 15, r4 = lane >> 4;

  const int koff = blockIdx.z * Kc;

  const unsigned short* ga = A  + (size_t)(m0 + (tid >> 2)) * K + koff + (tid & 3) * 8;
  const unsigned short* gb = B0 + (size_t)(n0 + (tid >> 2)) * K + koff + (tid & 3) * 8;
  const size_t rstep = (size_t)64 * K;
  const int lo = wave * 512;

  auto STAGE = [&](int slot, int tt) {
    const unsigned short* gaa = ga + tt * 32;
    const unsigned short* gbb = gb + tt * 32;
    gll16(gaa,         &As[slot][lo]);
    gll16(gaa + rstep, &As[slot][lo + 2048]);
    gll16(gbb,         &Bs[slot][lo]);
    gll16(gbb + rstep, &Bs[slot][lo + 2048]);
  };

  f32x4 acc[4][4] = {};
  const int NT = Kc >> 5;

  STAGE(0, 0);
  if (NT > 1) STAGE(1, 1);

  for (int t = 0; t < NT; t++) {
    if (t + 1 < NT) asm volatile("s_waitcnt vmcnt(4)" ::: "memory");
    else            asm volatile("s_waitcnt vmcnt(0)" ::: "memory");
    __builtin_amdgcn_sched_barrier(0);
    __builtin_amdgcn_s_barrier();
    __builtin_amdgcn_sched_barrier(0);

    const int slot = t & 1;
    bf16x8 av[4], bv[4];
#pragma unroll
    for (int mf = 0; mf < 4; mf++)
      av[mf] = *(const bf16x8*)&As[slot][(wm*64 + mf*16 + r16) * 32 + r4 * 8];
#pragma unroll
    for (int nf = 0; nf < 4; nf++)
      bv[nf] = *(const bf16x8*)&Bs[slot][(wn*64 + nf*16 + r16) * 32 + r4 * 8];
    asm volatile("s_waitcnt lgkmcnt(0)" ::: "memory");
    __builtin_amdgcn_sched_barrier(0);
    __builtin_amdgcn_s_barrier();
    __builtin_amdgcn_sched_barrier(0);

    if (t + 2 < NT) STAGE(slot, t + 2);

#pragma unroll
    for (int mf = 0; mf < 4; mf++)
#pragma unroll
      for (int nf = 0; nf < 4; nf++)
        acc[mf][nf] = mfma16(av[mf], bv[nf], acc[mf][nf]);
    __builtin_amdgcn_sched_barrier(0);
  }

  const int row0 = m0 + wm * 64, col0 = n0 + wn * 64;
  float* po = nullptr;
  if (EPI == 4)
    po = part + (size_t)blockIdx.z * ((size_t)gridDim.x * 128 * N);
  unsigned short* po16 = nullptr;
  if (EPI == 5)
    po16 = o0 + (size_t)blockIdx.z * 4194304;
#pragma unroll
  for (int mf = 0; mf < 4; mf++)
#pragma unroll
    for (int nf = 0; nf < 4; nf++)
#pragma unroll
      for (int jj = 0; jj < 4; jj++) {
        const int r = row0 + mf*16 + r4*4 + jj;
        const int c = col0 + nf*16 + r16;
        const float v = acc[mf][nf][jj];
        if (EPI == 4) po  [(size_t)r * N + c] = v;
        else          po16[(size_t)r * N + c] = f2bf(v);
      }
}

// ---------------------------------------------------------------------------
// 256x256 8-phase GEMM (T3+T4+T5), BK=64, 512 thr / 8 waves. (R12, passing.)
// EPI: 0 = QKV scatter (z selects Wq/Wk/Wv; q scaled 0.125; v transposed)
//      2 = relu(acc+bias)->bf16, 5 = bf16 split-K partial (o0 + z*4194304)
template<int EPI>
__global__ __launch_bounds__(512, 2)
void gemm8_k(const unsigned short* __restrict__ A,
             const unsigned short* __restrict__ B0,
             const unsigned short* __restrict__ B1,
             const unsigned short* __restrict__ B2,
             const float* __restrict__ bias,
             unsigned short* __restrict__ o0,
             unsigned short* __restrict__ o1,
             unsigned short* __restrict__ o2,
             int K, int N, int Kc)
{
  __shared__ __align__(16) unsigned short LA[2][2][8192];
  __shared__ __align__(16) unsigned short LB[2][2][8192];
  const int tid = threadIdx.x;
  const int wave = tid >> 6, lane = tid & 63;
  const int wm = wave >> 2, wn = wave & 3;
  const int r16 = lane & 15, r4 = lane >> 4;
  const int m0 = blockIdx.x * 256, n0 = blockIdx.y * 256;
  const int koff = (EPI == 5) ? blockIdx.z * Kc : 0;
  const int NT = Kc >> 6;

  const unsigned short* Bt = B0;
  if (EPI == 0) Bt = (blockIdx.z == 0) ? B0 : (blockIdx.z == 1) ? B1 : B2;

  const unsigned short* As0 = A  + (size_t)m0 * K + koff;
  const unsigned short* As1 = A  + (size_t)(m0 + 128) * K + koff;
  const unsigned short* Bs0 = Bt + (size_t)n0 * K + koff;
  const unsigned short* Bs1 = Bt + (size_t)(n0 + 128) * K + koff;

  auto STAGEH = [&](unsigned short* lds, const unsigned short* gsrc) {
    const int c0 = tid, r0 = c0 >> 3;
    gll16(gsrc + (size_t)r0 * K + ((c0 & 7) ^ (r0 & 7)) * 8, lds + c0 * 8);
    const int c1 = 512 + tid, r1 = c1 >> 3;
    gll16(gsrc + (size_t)r1 * K + ((c1 & 7) ^ (r1 & 7)) * 8, lds + c1 * 8);
  };

  f32x4 acc[8][4] = {};
  bf16x8 avx[4][2], bvx[2][2][2];

  STAGEH(&LB[0][0][0], Bs0);
  STAGEH(&LB[0][1][0], Bs1);
  STAGEH(&LA[0][0][0], As0);
  STAGEH(&LA[0][1][0], As1);
  if (NT > 1) {
    STAGEH(&LB[1][0][0], Bs0 + 64);
    STAGEH(&LB[1][1][0], Bs1 + 64);
  }

  for (int t = 0; t < NT; ++t) {
    const int slot = t & 1;
    if (t + 1 < NT) asm volatile("s_waitcnt vmcnt(4)" ::: "memory");
    else            asm volatile("s_waitcnt vmcnt(0)" ::: "memory");
    __builtin_amdgcn_sched_barrier(0);
    __builtin_amdgcn_s_barrier();
    __builtin_amdgcn_sched_barrier(0);

    // ---- p1: (qr0, qc0)
#pragma unroll
    for (int mfq = 0; mfq < 4; mfq++)
#pragma unroll
      for (int kk = 0; kk < 2; kk++)
        avx[mfq][kk] = *(const bf16x8*)&LA[slot][wm][
            (mfq*16 + r16) * 64 + (((kk*4 + r4) ^ (r16 & 7)) * 8)];
#pragma unroll
    for (int nfq = 0; nfq < 2; nfq++)
#pragma unroll
      for (int kk = 0; kk < 2; kk++)
        bvx[0][nfq][kk] = *(const bf16x8*)&LB[slot][wn >> 1][
            ((wn & 1)*64 + nfq*16 + r16) * 64 + (((kk*4 + r4) ^ (r16 & 7)) * 8)];
    if (t + 1 < NT) STAGEH(&LA[slot ^ 1][0][0], As0 + (t + 1) * 64);
    asm volatile("s_waitcnt lgkmcnt(0)" ::: "memory");
    __builtin_amdgcn_sched_barrier(0);
    __builtin_amdgcn_s_setprio(1);
#pragma unroll
    for (int mfq = 0; mfq < 4; mfq++)
#pragma unroll
      for (int nfq = 0; nfq < 2; nfq++)
#pragma unroll
        for (int kk = 0; kk < 2; kk++)
          acc[mfq][nfq] = mfma16(avx[mfq][kk], bvx[0][nfq][kk], acc[mfq][nfq]);
    __builtin_amdgcn_s_setprio(0);

    // ---- p2: (qr0, qc1)
#pragma unroll
    for (int nfq = 0; nfq < 2; nfq++)
#pragma unroll
      for (int kk = 0; kk < 2; kk++)
        bvx[1][nfq][kk] = *(const bf16x8*)&LB[slot][wn >> 1][
            ((wn & 1)*64 + 32 + nfq*16 + r16) * 64 + (((kk*4 + r4) ^ (r16 & 7)) * 8)];
    if (t + 1 < NT) STAGEH(&LA[slot ^ 1][1][0], As1 + (t + 1) * 64);
    asm volatile("s_waitcnt lgkmcnt(0)" ::: "memory");
    __builtin_amdgcn_sched_barrier(0);
    __builtin_amdgcn_s_setprio(1);
#pragma unroll
    for (int mfq = 0; mfq < 4; mfq++)
#pragma unroll
      for (int nfq = 0; nfq < 2; nfq++)
#pragma unroll
        for (int kk = 0; kk < 2; kk++)
          acc[mfq][2 + nfq] = mfma16(avx[mfq][kk], bvx[1][nfq][kk], acc[mfq][2 + nfq]);
    __builtin_amdgcn_s_setprio(0);

    __builtin_amdgcn_sched_barrier(0);
    __builtin_amdgcn_s_barrier();
    __builtin_amdgcn_sched_barrier(0);

    // ---- p3: (qr1, qc0)
#pragma unroll
    for (int mfq = 0; mfq < 4; mfq++)
#pragma unroll
      for (int kk = 0; kk < 2; kk++)
        avx[mfq][kk] = *(const bf16x8*)&LA[slot][wm][
            (64 + mfq*16 + r16) * 64 + (((kk*4 + r4) ^ (r16 & 7)) * 8)];
    if (t + 2 < NT) STAGEH(&LB[slot][0][0], Bs0 + (t + 2) * 64);
    asm volatile("s_waitcnt lgkmcnt(0)" ::: "memory");
    __builtin_amdgcn_sched_barrier(0);
    __builtin_amdgcn_s_setprio(1);
#pragma unroll
    for (int mfq = 0; mfq < 4; mfq++)
#pragma unroll
      for (int nfq = 0; nfq < 2; nfq++)
#pragma unroll
        for (int kk = 0; kk < 2; kk++)
          acc[4 + mfq][nfq] = mfma16(avx[mfq][kk], bvx[0][nfq][kk], acc[4 + mfq][nfq]);
    __builtin_amdgcn_s_setprio(0);

    // ---- p4: (qr1, qc1)
    if (t + 2 < NT) STAGEH(&LB[slot][1][0], Bs1 + (t + 2) * 64);
    __builtin_amdgcn_s_setprio(1);
#pragma unroll
    for (int mfq = 0; mfq < 4; mfq++)
#pragma unroll
      for (int nfq = 0; nfq < 2; nfq++)
#pragma unroll
        for (int kk = 0; kk < 2; kk++)
          acc[4 + mfq][2 + nfq] = mfma16(avx[mfq][kk], bvx[1][nfq][kk], acc[4 + mfq][2 + nfq]);
    __builtin_amdgcn_s_setprio(0);
    __builtin_amdgcn_sched_barrier(0);
  }

  // epilogue
  const int row0 = m0 + wm * 128, col0 = n0 + wn * 64;
  unsigned short* po16 = o0;
  if (EPI == 5) po16 = o0 + (size_t)blockIdx.z * 4194304;
#pragma unroll
  for (int mf = 0; mf < 8; mf++) {
#pragma unroll
    for (int nf = 0; nf < 4; nf++) {
#pragma unroll
      for (int jj = 0; jj < 4; jj++) {
        const int r = row0 + mf*16 + r4*4 + jj;
        const int c = col0 + nf*16 + r16;
        const float v = acc[mf][nf][jj];
        if (EPI == 0) {
          const int z = blockIdx.z;
          const int b_ = r >> 10, s_ = r & 1023;
          const int hh = c >> 6, e = c & 63;
          if (z == 0)
            o0[((size_t)(b_*16 + hh) * 1024 + s_) * 64 + e] = f2bf(v * 0.125f);
          else if (z == 1)
            o1[((size_t)(b_*16 + hh) * 1024 + s_) * 64 + e] = f2bf(v);
          else
            o2[((size_t)(b_*16 + hh) * 64 + e) * 1024 + s_] = f2bf(v);
        } else if (EPI == 2) {
          const float t2 = v + bias[c];
          po16[(size_t)r * N + c] = f2bf(t2 > 0.f ? t2 : 0.f);
        } else {
          po16[(size_t)r * N + c] = f2bf(v);
        }
      }
    }
  }
}

// ---------------------------------------------------------------------------
// Split-K reduce (f32 partials, logits path): outw = sum + bias.
__global__ __launch_bounds__(256)
void red_k(const float* __restrict__ part, const float* __restrict__ bias,
           float* __restrict__ outw, int n4, int nm4, int KZ)
{
  const float4* p4 = (const float4*)part;
  const float4* b4 = (const float4*)bias;
  for (size_t i = (size_t)blockIdx.x * 256 + threadIdx.x; i < (size_t)n4;
       i += (size_t)gridDim.x * 256) {
    float4 s = p4[i];
    for (int kz = 1; kz < KZ; kz++) {
      float4 t = p4[i + (size_t)kz * n4];
      s.x += t.x; s.y += t.y; s.z += t.z; s.w += t.w;
    }
    float4 bv = b4[i & nm4];
    s.x += bv.x; s.y += bv.y; s.z += bv.z; s.w += bv.w;
    ((float4*)outw)[i] = s;
  }
}

// ---------------------------------------------------------------------------
// Flash attention, counted-vmcnt pipeline + fixed-shift softmax. (R11/R12,
// passing.) 1024 blocks x 256 thr (4 waves), QBLK=64, KVBLK=64.
__global__ __launch_bounds__(256)
void attn_k(const unsigned short* __restrict__ qb,
            const unsigned short* __restrict__ kb,
            const unsigned short* __restrict__ vtb,
            unsigned short* __restrict__ att)
{
  __shared__ __align__(16) unsigned short Ks[2][64 * 64];
  __shared__ __align__(16) unsigned short Vs[2][64 * 64];
  __shared__ __align__(16) unsigned short Ps[64 * 72];
  const int flat = blockIdx.x;
  const int job  = (flat & 7) * 128 + (flat >> 3);
  const int qt   = 15 - (job & 15);
  const int h    = (job >> 4) & 15;
  const int b    = job >> 8;
  const int tid = threadIdx.x, wave = tid >> 6, lane = tid & 63;
  const int r16 = lane & 15, r4 = lane >> 4;
  const int q0 = qt * 64;
  const size_t bh = (size_t)(b * 16 + h);
  const unsigned short* qbh = qb  + bh * 1024 * 64;
  const unsigned short* kbh = kb  + bh * 1024 * 64;
  const unsigned short* vbh = vtb + bh * 64 * 1024;

  const int swz = ((lane & 7) ^ (lane >> 3)) * 8;
  const int srow = lane >> 3;

  auto STAGE = [&](int slot, int tt) {
    const int kv0 = tt * 64;
#pragma unroll
    for (int cc = 0; cc < 2; cc++) {
      const int chunk = wave * 2 + cc;
      gll16(kbh + (size_t)(kv0 + chunk*8 + srow) * 64 + swz,   &Ks[slot][chunk * 512]);
      gll16(vbh + (size_t)(chunk*8 + srow) * 1024 + kv0 + swz, &Vs[slot][chunk * 512]);
    }
  };

  bf16x8 qf[2];
#pragma unroll
  for (int kc = 0; kc < 2; kc++)
    qf[kc] = *(const bf16x8*)&qbh[(size_t)(q0 + wave*16 + r16) * 64 + kc*32 + r4*8];

  f32x4 oacc[4] = {};
  float l_i[4] = {0.f, 0.f, 0.f, 0.f};

  const int nt = qt + 1;

  STAGE(0, 0);
  if (nt > 1) STAGE(1, 1);

  for (int t = 0; t < nt; t++) {
    if (t + 1 < nt) asm volatile("s_waitcnt vmcnt(4)" ::: "memory");
    else            asm volatile("s_waitcnt vmcnt(0)" ::: "memory");
    __builtin_amdgcn_sched_barrier(0);
    __builtin_amdgcn_s_barrier();
    __builtin_amdgcn_sched_barrier(0);

    const int slot = t & 1;
    bf16x8 kf[2][4], vf[2][4];
#pragma unroll
    for (int kc = 0; kc < 2; kc++)
#pragma unroll
      for (int nf = 0; nf < 4; nf++) {
        kf[kc][nf] = *(const bf16x8*)&Ks[slot][(nf*16 + r16) * 64 +
                                              (((kc*4 + r4) ^ (r16 & 7)) * 8)];
        vf[kc][nf] = *(const bf16x8*)&Vs[slot][(nf*16 + r16) * 64 +
                                              (((kc*4 + r4) ^ (r16 & 7)) * 8)];
      }
    asm volatile("s_waitcnt lgkmcnt(0)" ::: "memory");
    __builtin_amdgcn_sched_barrier(0);
    __builtin_amdgcn_s_barrier();
    __builtin_amdgcn_sched_barrier(0);

    if (t + 2 < nt) STAGE(slot, t + 2);

    f32x4 sacc[4] = {};
#pragma unroll
    for (int kc = 0; kc < 2; kc++)
#pragma unroll
      for (int nf = 0; nf < 4; nf++)
        sacc[nf] = mfma16(qf[kc], kf[kc][nf], sacc[nf]);

    const bool diag = (t == nt - 1);
#pragma unroll
    for (int jj = 0; jj < 4; jj++) {
      float vv[4];
#pragma unroll
      for (int nf = 0; nf < 4; nf++) vv[nf] = sacc[nf][jj];
      if (diag) {
        const int qrow_l = wave*16 + r4*4 + jj;
#pragma unroll
        for (int nf = 0; nf < 4; nf++)
          if (nf*16 + r16 > qrow_l) vv[nf] = -1e30f;
      }
      float p0 = __expf(vv[0]), p1 = __expf(vv[1]);
      float p2 = __expf(vv[2]), p3 = __expf(vv[3]);
      l_i[jj] += (p0 + p1) + (p2 + p3);
      const int prow = (wave*16 + r4*4 + jj) * 72;
      Ps[prow + r16     ] = f2bf(p0);
      Ps[prow + 16 + r16] = f2bf(p1);
      Ps[prow + 32 + r16] = f2bf(p2);
      Ps[prow + 48 + r16] = f2bf(p3);
    }

#pragma unroll
    for (int kc = 0; kc < 2; kc++) {
      bf16x8 pf = *(const bf16x8*)&Ps[(wave*16 + r16) * 72 + kc*32 + r4*8];
#pragma unroll
      for (int nh = 0; nh < 4; nh++)
        oacc[nh] = mfma16(pf, vf[kc][nh], oacc[nh]);
    }
    __builtin_amdgcn_sched_barrier(0);
  }

#pragma unroll
  for (int jj = 0; jj < 4; jj++)
#pragma unroll
    for (int mk = 8; mk >= 1; mk >>= 1) l_i[jj] += __shfl_xor(l_i[jj], mk);

#pragma unroll
  for (int nh = 0; nh < 4; nh++) {
#pragma unroll
    for (int jj = 0; jj < 4; jj++) {
      const int row = q0 + wave*16 + r4*4 + jj;
      const int col = nh*16 + r16;
      const float o = oacc[nh][jj] / l_i[jj];
      att[(size_t)(b * 1024 + row) * 1024 + h*64 + col] = f2bf(o);
    }
  }
}

// ---------------------------------------------------------------------------
extern "C" void kernel_launch(void* const* d_in, const int* in_sizes, int n_in,
                              void* d_out, int out_size, void* d_ws, size_t ws_size,
                              hipStream_t stream)
{
  const int*   toks    = (const int*)  d_in[0];
  const float* tok_emb = (const float*)d_in[1];
  const float* pos_emb = (const float*)d_in[2];
  const float* Wq      = (const float*)d_in[3];
  const float* Wk      = (const float*)d_in[4];
  const float* Wv      = (const float*)d_in[5];
  const float* Wo      = (const float*)d_in[6];
  const float* bo      = (const float*)d_in[7];
  const float* ln1_g   = (const float*)d_in[8];
  const float* ln1_b   = (const float*)d_in[9];
  const float* ln2_g   = (const float*)d_in[10];
  const float* ln2_b   = (const float*)d_in[11];
  const float* W1      = (const float*)d_in[12];
  const float* b1      = (const float*)d_in[13];
  const float* W2      = (const float*)d_in[14];
  const float* b2      = (const float*)d_in[15];
  const float* lnf_g   = (const float*)d_in[16];
  const float* lnf_b   = (const float*)d_in[17];
  const float* Wout    = (const float*)d_in[18];
  const float* bout    = (const float*)d_in[19];
  float* out = (float*)d_out;

  char* w = (char*)d_ws;
  size_t off = 0;
  auto alloc = [&](size_t bytes) -> void* {
    void* p = w + off; off += (bytes + 255) & ~(size_t)255; return p;
  };
  unsigned short* wqT   = (unsigned short*)alloc(8ull*1024*1024*2);
  unsigned short* wkT   = (unsigned short*)alloc(8ull*1024*1024*2);
  unsigned short* wvT   = (unsigned short*)alloc(8ull*1024*1024*2);
  unsigned short* woT   = (unsigned short*)alloc(8ull*1024*1024*2);
  unsigned short* w1T   = (unsigned short*)alloc(8ull*1024*4096*2);
  unsigned short* w2T   = (unsigned short*)alloc(8ull*4096*1024*2);
  unsigned short* woutT = (unsigned short*)alloc(256ull*1024*2);
  float*          x     = (float*)         alloc(4096ull*1024*4);
  unsigned short* hbuf  = (unsigned short*)alloc(4096ull*1024*2);
  unsigned short* qbuf  = (unsigned short*)alloc(64ull*1024*64*2);
  unsigned short* kbuf  = (unsigned short*)alloc(64ull*1024*64*2);
  unsigned short* vtb   = (unsigned short*)alloc(64ull*1024*64*2);
  unsigned short* att   = (unsigned short*)alloc(4096ull*1024*2);
  unsigned short* ff    = (unsigned short*)alloc(4096ull*4096*2);
  unsigned short* part16= (unsigned short*)alloc(4ull*4194304*2);   // bf16 split-K partials
  float*          part  = (float*)         alloc(8ull*1048576*4);   // f32 partials (logits)
  (void)ws_size; (void)in_sizes; (void)n_in; (void)out_size;

  dim3 tb(32, 8);
  tcvt_k<<<dim3(32, 32, 8),  tb, 0, stream>>>(Wq,   wqT,   1024, 1024);
  tcvt_k<<<dim3(32, 32, 8),  tb, 0, stream>>>(Wk,   wkT,   1024, 1024);
  tcvt_k<<<dim3(32, 32, 8),  tb, 0, stream>>>(Wv,   wvT,   1024, 1024);
  tcvt_k<<<dim3(32, 32, 8),  tb, 0, stream>>>(Wo,   woT,   1024, 1024);
  tcvt_k<<<dim3(128, 32, 8), tb, 0, stream>>>(W1,   w1T,   1024, 4096);
  tcvt_k<<<dim3(32, 128, 8), tb, 0, stream>>>(W2,   w2T,   4096, 1024);
  tcvt_k<<<dim3(8, 32, 1),   tb, 0, stream>>>(Wout, woutT, 1024, 256);

  // embed + layer-0 LN1 fused
  embed_ln_k<<<4096, 256, 0, stream>>>(toks, tok_emb, pos_emb,
                                       ln1_g, ln1_b, x, hbuf);

  for (int l = 0; l < 8; l++) {
    // QKV: 256^2 8-phase, z selects Wq/Wk/Wv, scatter epilogue  [THE ONE CHANGE]
    gemm8_k<0><<<dim3(16, 4, 3), 512, 0, stream>>>(hbuf,
        wqT + (size_t)l*1048576, wkT + (size_t)l*1048576, wvT + (size_t)l*1048576,
        nullptr, qbuf, kbuf, vtb, 1024, 1024, 1024);
    attn_k<<<1024, 256, 0, stream>>>(qbuf, kbuf, vtb, att);
    // Wo: 128^2 split-K x4 (Kc=256) -> bf16 partials, fused reduce+LN2
    gemm_k<5><<<dim3(32, 8, 4), 256, 0, stream>>>(att,
        woT + (size_t)l*1048576, part16, 1024, 1024, 256, nullptr);
    redln_k<<<4096, 256, 0, stream>>>(part16, bo + l*1024,
        ln2_g + l*1024, ln2_b + l*1024, x, hbuf);
    // FFN1: 256^2 8-phase, relu -> bf16 ff
    gemm8_k<2><<<dim3(16, 16), 512, 0, stream>>>(hbuf,
        w1T + (size_t)l*4194304, nullptr, nullptr,
        b1 + l*4096, ff, nullptr, nullptr, 1024, 4096, 1024);
    // FFN2: 256^2 8-phase split-K x4 (Kc=1024) -> bf16 partials
    gemm8_k<5><<<dim3(16, 4, 4), 512, 0, stream>>>(ff,
        w2T + (size_t)l*4194304, nullptr, nullptr,
        nullptr, part16, nullptr, nullptr, 4096, 1024, 1024);
    if (l < 7)
      redln_k<<<4096, 256, 0, stream>>>(part16, b2 + l*1024,
          ln1_g + (l+1)*1024, ln1_b + (l+1)*1024, x, hbuf);
    else
      redln_k<<<4096, 256, 0, stream>>>(part16, b2 + l*1024,
          lnf_g, lnf_b, x, hbuf);
  }

  // logits: split-K x8 (Kc=128, f32 partials), then bias-reduce into out
  gemm_k<4><<<dim3(32, 2, 8), 256, 0, stream>>>(hbuf, woutT, nullptr,
      1024, 256, 128, part);
  red_k<<<1024, 256, 0, stream>>>(part, bout, out, 262144, 63, 8);
}

// Round 15
// 1778.290 us; speedup vs baseline: 1.0387x; 1.0212x over previous
//
#include <hip/hip_runtime.h>

#define DEV __device__ __forceinline__

typedef __bf16 bf16x8 __attribute__((ext_vector_type(8)));
typedef float  f32x4  __attribute__((ext_vector_type(4)));

typedef const __attribute__((address_space(1))) unsigned int* gas_ptr;
typedef       __attribute__((address_space(3))) unsigned int* las_ptr;

DEV unsigned short f2bf(float f) {
  union { __bf16 h; unsigned short u; } c; c.h = (__bf16)f; return c.u;
}

DEV float bf2f(unsigned short u) {
  union { unsigned int i; float f; } c; c.i = (unsigned int)u << 16; return c.f;
}

DEV void gll16(const void* g, void* l) {
  __builtin_amdgcn_global_load_lds((gas_ptr)g, (las_ptr)l, 16, 0, 0);
}

DEV f32x4 mfma16(bf16x8 a, bf16x8 b, f32x4 c) {
  return __builtin_amdgcn_mfma_f32_16x16x32_bf16(a, b, c, 0, 0, 0);
}

// ---------------------------------------------------------------------------
// Transpose + f32->bf16 convert: src [K,N] f32 -> dst [N,K] bf16. grid.z = layer.
__global__ __launch_bounds__(256)
void tcvt_k(const float* __restrict__ src, unsigned short* __restrict__ dst,
            int K, int N)
{
  __shared__ float t[32][33];
  const int tx = threadIdx.x, ty = threadIdx.y;
  const size_t mo = (size_t)blockIdx.z * K * N;
  const int n0 = blockIdx.x * 32, k0 = blockIdx.y * 32;
  const float* s = src + mo;
  unsigned short* d = dst + mo;
#pragma unroll
  for (int i = 0; i < 4; i++)
    t[ty + i*8][tx] = s[(size_t)(k0 + ty + i*8) * N + n0 + tx];
  __syncthreads();
#pragma unroll
  for (int i = 0; i < 4; i++)
    d[(size_t)(n0 + ty + i*8) * K + k0 + tx] = f2bf(t[tx][ty + i*8]);
}

// ---------------------------------------------------------------------------
// Shared LN tail
DEV void ln_tail(float4 s, const float* __restrict__ g,
                 const float* __restrict__ bta,
                 unsigned short* __restrict__ hrow, int t, float* red)
{
  float sm  = s.x + s.y + s.z + s.w;
  float sq = s.x*s.x + s.y*s.y + s.z*s.z + s.w*s.w;
#pragma unroll
  for (int mk = 32; mk >= 1; mk >>= 1) {
    sm += __shfl_xor(sm, mk);
    sq += __shfl_xor(sq, mk);
  }
  const int wv = t >> 6;
  if ((t & 63) == 0) { red[wv] = sm; red[4 + wv] = sq; }
  __syncthreads();
  sm = red[0] + red[1] + red[2] + red[3];
  sq = red[4] + red[5] + red[6] + red[7];
  const float mu = sm * (1.f/1024.f);
  const float rs = rsqrtf(sq * (1.f/1024.f) - mu*mu + 1e-5f);
  const float4 gv = ((const float4*)g)[t];
  const float4 bv = ((const float4*)bta)[t];
  ushort4 o;
  o.x = f2bf((s.x - mu) * rs * gv.x + bv.x);
  o.y = f2bf((s.y - mu) * rs * gv.y + bv.y);
  o.z = f2bf((s.z - mu) * rs * gv.z + bv.z);
  o.w = f2bf((s.w - mu) * rs * gv.w + bv.w);
  ((ushort4*)hrow)[t] = o;
}

// ---------------------------------------------------------------------------
// Embedding + LN1(layer0)
__global__ __launch_bounds__(256)
void embed_ln_k(const int* __restrict__ toks, const float* __restrict__ te,
                const float* __restrict__ pe, const float* __restrict__ g,
                const float* __restrict__ bta,
                float* __restrict__ x, unsigned short* __restrict__ h)
{
  __shared__ float red[8];
  const int row = blockIdx.x, t = threadIdx.x;
  const int tok = toks[row], s = row & 1023;
  float4 a = ((const float4*)(te + (size_t)tok * 1024))[t];
  float4 p = ((const float4*)(pe + (size_t)s   * 1024))[t];
  float4 v; v.x = a.x+p.x; v.y = a.y+p.y; v.z = a.z+p.z; v.w = a.w+p.w;
  ((float4*)(x + (size_t)row * 1024))[t] = v;
  ln_tail(v, g, bta, h + (size_t)row * 1024, t, red);
}

// ---------------------------------------------------------------------------
// Fused split-K reduce (4 bf16 partials) + residual + bias + LayerNorm.
__global__ __launch_bounds__(256)
void redln_k(const unsigned short* __restrict__ part,
             const float* __restrict__ bias,
             const float* __restrict__ g, const float* __restrict__ bta,
             float* __restrict__ x, unsigned short* __restrict__ h)
{
  __shared__ float red[8];
  const int row = blockIdx.x, t = threadIdx.x;
  const size_t pbase = (size_t)row * 1024 + t * 4;
  float a0 = 0.f, a1 = 0.f, a2 = 0.f, a3 = 0.f;
#pragma unroll
  for (int kz = 0; kz < 4; kz++) {
    ushort4 u = *(const ushort4*)&part[(size_t)kz * 4194304 + pbase];
    a0 += bf2f(u.x); a1 += bf2f(u.y); a2 += bf2f(u.z); a3 += bf2f(u.w);
  }
  float4 xv = ((const float4*)(x + (size_t)row * 1024))[t];
  float4 bv = ((const float4*)bias)[t];
  float4 s;
  s.x = xv.x + a0 + bv.x; s.y = xv.y + a1 + bv.y;
  s.z = xv.z + a2 + bv.z; s.w = xv.w + a3 + bv.w;
  ((float4*)(x + (size_t)row * 1024))[t] = s;
  ln_tail(s, g, bta, h + (size_t)row * 1024, t, red);
}

// ---------------------------------------------------------------------------
// bf16 GEMM, m97 structure + counted-vmcnt double-buffer. (R8/R12, passing.)
// EPI: 0 = QKV scatter (z selects Wq/Wk/Wv; q scaled 0.125; v transposed)
//      4 = split-K f32 partial  5 = split-K bf16 partial (o0 + z*4194304)
template<int EPI>
__global__ __launch_bounds__(256)
void gemm_k(const unsigned short* __restrict__ A,
            const unsigned short* __restrict__ B0,
            const unsigned short* __restrict__ B1,
            const unsigned short* __restrict__ B2,
            unsigned short* __restrict__ o0,
            unsigned short* __restrict__ o1,
            unsigned short* __restrict__ o2,
            int K, int N, int Kc, float* __restrict__ part)
{
  __shared__ __align__(16) unsigned short As[2][128 * 32];
  __shared__ __align__(16) unsigned short Bs[2][128 * 32];
  const int tid = threadIdx.x;
  const int wave = tid >> 6, lane = tid & 63;
  const int wm = wave >> 1, wn = wave & 1;
  const int m0 = blockIdx.x * 128, n0 = blockIdx.y * 128;
  const int r16 = lane & 15, r4 = lane >> 4;

  const unsigned short* Bt = B0;
  if (EPI == 0) Bt = (blockIdx.z == 0) ? B0 : (blockIdx.z == 1) ? B1 : B2;
  const int koff = (EPI >= 4) ? blockIdx.z * Kc : 0;
  const int klen = (EPI >= 4) ? Kc : K;

  const unsigned short* ga = A  + (size_t)(m0 + (tid >> 2)) * K + koff + (tid & 3) * 8;
  const unsigned short* gb = Bt + (size_t)(n0 + (tid >> 2)) * K + koff + (tid & 3) * 8;
  const size_t rstep = (size_t)64 * K;
  const int lo = wave * 512;

  auto STAGE = [&](int slot, int tt) {
    const unsigned short* gaa = ga + tt * 32;
    const unsigned short* gbb = gb + tt * 32;
    gll16(gaa,         &As[slot][lo]);
    gll16(gaa + rstep, &As[slot][lo + 2048]);
    gll16(gbb,         &Bs[slot][lo]);
    gll16(gbb + rstep, &Bs[slot][lo + 2048]);
  };

  f32x4 acc[4][4] = {};
  const int NT = klen >> 5;

  STAGE(0, 0);
  if (NT > 1) STAGE(1, 1);

  for (int t = 0; t < NT; t++) {
    if (t + 1 < NT) asm volatile("s_waitcnt vmcnt(4)" ::: "memory");
    else            asm volatile("s_waitcnt vmcnt(0)" ::: "memory");
    __builtin_amdgcn_sched_barrier(0);
    __builtin_amdgcn_s_barrier();
    __builtin_amdgcn_sched_barrier(0);

    const int slot = t & 1;
    bf16x8 av[4], bv[4];
#pragma unroll
    for (int mf = 0; mf < 4; mf++)
      av[mf] = *(const bf16x8*)&As[slot][(wm*64 + mf*16 + r16) * 32 + r4 * 8];
#pragma unroll
    for (int nf = 0; nf < 4; nf++)
      bv[nf] = *(const bf16x8*)&Bs[slot][(wn*64 + nf*16 + r16) * 32 + r4 * 8];
    asm volatile("s_waitcnt lgkmcnt(0)" ::: "memory");
    __builtin_amdgcn_sched_barrier(0);
    __builtin_amdgcn_s_barrier();
    __builtin_amdgcn_sched_barrier(0);

    if (t + 2 < NT) STAGE(slot, t + 2);

#pragma unroll
    for (int mf = 0; mf < 4; mf++)
#pragma unroll
      for (int nf = 0; nf < 4; nf++)
        acc[mf][nf] = mfma16(av[mf], bv[nf], acc[mf][nf]);
    __builtin_amdgcn_sched_barrier(0);
  }

  const int row0 = m0 + wm * 64, col0 = n0 + wn * 64;
  float* po = nullptr;
  if (EPI == 4)
    po = part + (size_t)blockIdx.z * ((size_t)gridDim.x * 128 * N);
  unsigned short* po16 = nullptr;
  if (EPI == 5)
    po16 = o0 + (size_t)blockIdx.z * 4194304;
#pragma unroll
  for (int mf = 0; mf < 4; mf++) {
#pragma unroll
    for (int nf = 0; nf < 4; nf++) {
#pragma unroll
      for (int jj = 0; jj < 4; jj++) {
        const int r = row0 + mf*16 + r4*4 + jj;
        const int c = col0 + nf*16 + r16;
        const float v = acc[mf][nf][jj];
        if (EPI == 0) {
          const int z = blockIdx.z;
          const int b_ = r >> 10, s_ = r & 1023;
          const int hh = c >> 6, e = c & 63;
          if (z == 0)
            o0[((size_t)(b_*16 + hh) * 1024 + s_) * 64 + e] = f2bf(v * 0.125f);
          else if (z == 1)
            o1[((size_t)(b_*16 + hh) * 1024 + s_) * 64 + e] = f2bf(v);
          else
            o2[((size_t)(b_*16 + hh) * 64 + e) * 1024 + s_] = f2bf(v);
        } else if (EPI == 4) {
          po[(size_t)r * N + c] = v;
        } else {
          po16[(size_t)r * N + c] = f2bf(v);
        }
      }
    }
  }
}

// ---------------------------------------------------------------------------
// 256x256 8-phase GEMM (T3+T4+T5), BK=64, 512 thr / 8 waves. (R12, passing.)
// NOTE: 128KB LDS -> 1 block/CU; only use with grid >= 256 blocks (FFN1/FFN2).
// EPI: 2 = relu(acc+bias)->bf16, 5 = bf16 split-K partial (o0 + z*4194304)
template<int EPI>
__global__ __launch_bounds__(512, 2)
void gemm8_k(const unsigned short* __restrict__ A,
             const unsigned short* __restrict__ Bt,
             const float* __restrict__ bias,
             unsigned short* __restrict__ o0,
             int K, int N, int Kc)
{
  __shared__ __align__(16) unsigned short LA[2][2][8192];
  __shared__ __align__(16) unsigned short LB[2][2][8192];
  const int tid = threadIdx.x;
  const int wave = tid >> 6, lane = tid & 63;
  const int wm = wave >> 2, wn = wave & 3;
  const int r16 = lane & 15, r4 = lane >> 4;
  const int m0 = blockIdx.x * 256, n0 = blockIdx.y * 256;
  const int koff = (EPI == 5) ? blockIdx.z * Kc : 0;
  const int NT = Kc >> 6;

  const unsigned short* As0 = A  + (size_t)m0 * K + koff;
  const unsigned short* As1 = A  + (size_t)(m0 + 128) * K + koff;
  const unsigned short* Bs0 = Bt + (size_t)n0 * K + koff;
  const unsigned short* Bs1 = Bt + (size_t)(n0 + 128) * K + koff;

  auto STAGEH = [&](unsigned short* lds, const unsigned short* gsrc) {
    const int c0 = tid, r0 = c0 >> 3;
    gll16(gsrc + (size_t)r0 * K + ((c0 & 7) ^ (r0 & 7)) * 8, lds + c0 * 8);
    const int c1 = 512 + tid, r1 = c1 >> 3;
    gll16(gsrc + (size_t)r1 * K + ((c1 & 7) ^ (r1 & 7)) * 8, lds + c1 * 8);
  };

  f32x4 acc[8][4] = {};
  bf16x8 avx[4][2], bvx[2][2][2];

  STAGEH(&LB[0][0][0], Bs0);
  STAGEH(&LB[0][1][0], Bs1);
  STAGEH(&LA[0][0][0], As0);
  STAGEH(&LA[0][1][0], As1);
  if (NT > 1) {
    STAGEH(&LB[1][0][0], Bs0 + 64);
    STAGEH(&LB[1][1][0], Bs1 + 64);
  }

  for (int t = 0; t < NT; ++t) {
    const int slot = t & 1;
    if (t + 1 < NT) asm volatile("s_waitcnt vmcnt(4)" ::: "memory");
    else            asm volatile("s_waitcnt vmcnt(0)" ::: "memory");
    __builtin_amdgcn_sched_barrier(0);
    __builtin_amdgcn_s_barrier();
    __builtin_amdgcn_sched_barrier(0);

    // ---- p1: (qr0, qc0)
#pragma unroll
    for (int mfq = 0; mfq < 4; mfq++)
#pragma unroll
      for (int kk = 0; kk < 2; kk++)
        avx[mfq][kk] = *(const bf16x8*)&LA[slot][wm][
            (mfq*16 + r16) * 64 + (((kk*4 + r4) ^ (r16 & 7)) * 8)];
#pragma unroll
    for (int nfq = 0; nfq < 2; nfq++)
#pragma unroll
      for (int kk = 0; kk < 2; kk++)
        bvx[0][nfq][kk] = *(const bf16x8*)&LB[slot][wn >> 1][
            ((wn & 1)*64 + nfq*16 + r16) * 64 + (((kk*4 + r4) ^ (r16 & 7)) * 8)];
    if (t + 1 < NT) STAGEH(&LA[slot ^ 1][0][0], As0 + (t + 1) * 64);
    asm volatile("s_waitcnt lgkmcnt(0)" ::: "memory");
    __builtin_amdgcn_sched_barrier(0);
    __builtin_amdgcn_s_setprio(1);
#pragma unroll
    for (int mfq = 0; mfq < 4; mfq++)
#pragma unroll
      for (int nfq = 0; nfq < 2; nfq++)
#pragma unroll
        for (int kk = 0; kk < 2; kk++)
          acc[mfq][nfq] = mfma16(avx[mfq][kk], bvx[0][nfq][kk], acc[mfq][nfq]);
    __builtin_amdgcn_s_setprio(0);

    // ---- p2: (qr0, qc1)
#pragma unroll
    for (int nfq = 0; nfq < 2; nfq++)
#pragma unroll
      for (int kk = 0; kk < 2; kk++)
        bvx[1][nfq][kk] = *(const bf16x8*)&LB[slot][wn >> 1][
            ((wn & 1)*64 + 32 + nfq*16 + r16) * 64 + (((kk*4 + r4) ^ (r16 & 7)) * 8)];
    if (t + 1 < NT) STAGEH(&LA[slot ^ 1][1][0], As1 + (t + 1) * 64);
    asm volatile("s_waitcnt lgkmcnt(0)" ::: "memory");
    __builtin_amdgcn_sched_barrier(0);
    __builtin_amdgcn_s_setprio(1);
#pragma unroll
    for (int mfq = 0; mfq < 4; mfq++)
#pragma unroll
      for (int nfq = 0; nfq < 2; nfq++)
#pragma unroll
        for (int kk = 0; kk < 2; kk++)
          acc[mfq][2 + nfq] = mfma16(avx[mfq][kk], bvx[1][nfq][kk], acc[mfq][2 + nfq]);
    __builtin_amdgcn_s_setprio(0);

    __builtin_amdgcn_sched_barrier(0);
    __builtin_amdgcn_s_barrier();
    __builtin_amdgcn_sched_barrier(0);

    // ---- p3: (qr1, qc0)
#pragma unroll
    for (int mfq = 0; mfq < 4; mfq++)
#pragma unroll
      for (int kk = 0; kk < 2; kk++)
        avx[mfq][kk] = *(const bf16x8*)&LA[slot][wm][
            (64 + mfq*16 + r16) * 64 + (((kk*4 + r4) ^ (r16 & 7)) * 8)];
    if (t + 2 < NT) STAGEH(&LB[slot][0][0], Bs0 + (t + 2) * 64);
    asm volatile("s_waitcnt lgkmcnt(0)" ::: "memory");
    __builtin_amdgcn_sched_barrier(0);
    __builtin_amdgcn_s_setprio(1);
#pragma unroll
    for (int mfq = 0; mfq < 4; mfq++)
#pragma unroll
      for (int nfq = 0; nfq < 2; nfq++)
#pragma unroll
        for (int kk = 0; kk < 2; kk++)
          acc[4 + mfq][nfq] = mfma16(avx[mfq][kk], bvx[0][nfq][kk], acc[4 + mfq][nfq]);
    __builtin_amdgcn_s_setprio(0);

    // ---- p4: (qr1, qc1)
    if (t + 2 < NT) STAGEH(&LB[slot][1][0], Bs1 + (t + 2) * 64);
    __builtin_amdgcn_s_setprio(1);
#pragma unroll
    for (int mfq = 0; mfq < 4; mfq++)
#pragma unroll
      for (int nfq = 0; nfq < 2; nfq++)
#pragma unroll
        for (int kk = 0; kk < 2; kk++)
          acc[4 + mfq][2 + nfq] = mfma16(avx[mfq][kk], bvx[1][nfq][kk], acc[4 + mfq][2 + nfq]);
    __builtin_amdgcn_s_setprio(0);
    __builtin_amdgcn_sched_barrier(0);
  }

  // epilogue
  const int row0 = m0 + wm * 128, col0 = n0 + wn * 64;
  unsigned short* po16 = o0;
  if (EPI == 5) po16 = o0 + (size_t)blockIdx.z * 4194304;
#pragma unroll
  for (int mf = 0; mf < 8; mf++) {
#pragma unroll
    for (int nf = 0; nf < 4; nf++) {
#pragma unroll
      for (int jj = 0; jj < 4; jj++) {
        const int r = row0 + mf*16 + r4*4 + jj;
        const int c = col0 + nf*16 + r16;
        const float v = acc[mf][nf][jj];
        if (EPI == 2) {
          const float t2 = v + bias[c];
          po16[(size_t)r * N + c] = f2bf(t2 > 0.f ? t2 : 0.f);
        } else {
          po16[(size_t)r * N + c] = f2bf(v);
        }
      }
    }
  }
}

// ---------------------------------------------------------------------------
// Split-K reduce (f32 partials, logits path): outw = sum + bias.
__global__ __launch_bounds__(256)
void red_k(const float* __restrict__ part, const float* __restrict__ bias,
           float* __restrict__ outw, int n4, int nm4, int KZ)
{
  const float4* p4 = (const float4*)part;
  const float4* b4 = (const float4*)bias;
  for (size_t i = (size_t)blockIdx.x * 256 + threadIdx.x; i < (size_t)n4;
       i += (size_t)gridDim.x * 256) {
    float4 s = p4[i];
    for (int kz = 1; kz < KZ; kz++) {
      float4 t = p4[i + (size_t)kz * n4];
      s.x += t.x; s.y += t.y; s.z += t.z; s.w += t.w;
    }
    float4 bv = b4[i & nm4];
    s.x += bv.x; s.y += bv.y; s.z += bv.z; s.w += bv.w;
    ((float4*)outw)[i] = s;
  }
}

// ---------------------------------------------------------------------------
// Flash attention v2 (THE ONE CHANGE vs R12): 512 thr / 8 waves, QBLK=128,
// KVBLK=64 -> per-(b,h) tile count 136 -> 72 (staging+barrier work ~halved).
// Counted-vmcnt (2 loads/tile/wave -> vmcnt(2)), fixed-shift softmax, T2
// swizzle, wave-uniform skip of fully-masked tiles (skipped waves still stage
// and hit both barriers -> sync audit unchanged). LDS 50KB. Grid 512 flat.
__global__ __launch_bounds__(512)
void attn_k(const unsigned short* __restrict__ qb,
            const unsigned short* __restrict__ kb,
            const unsigned short* __restrict__ vtb,
            unsigned short* __restrict__ att)
{
  __shared__ __align__(16) unsigned short Ks[2][64 * 64];
  __shared__ __align__(16) unsigned short Vs[2][64 * 64];
  __shared__ __align__(16) unsigned short Ps[128 * 72];
  const int flat = blockIdx.x;
  const int job  = (flat & 7) * 64 + (flat >> 3);   // XCD-contiguous decode
  const int qt   = 7 - (job & 7);                   // longest-first in chunk
  const int h    = (job >> 3) & 15;
  const int b    = job >> 7;
  const int tid = threadIdx.x, wave = tid >> 6, lane = tid & 63;
  const int r16 = lane & 15, r4 = lane >> 4;
  const int q0 = qt * 128;
  const size_t bh = (size_t)(b * 16 + h);
  const unsigned short* qbh = qb  + bh * 1024 * 64;
  const unsigned short* kbh = kb  + bh * 1024 * 64;
  const unsigned short* vbh = vtb + bh * 64 * 1024;

  // stage: 512 thr x 16B = one full 64x64 bf16 tile per array per call.
  const int srow = tid >> 3;
  const int swz  = ((tid & 7) ^ (srow & 7)) * 8;
  auto STAGE = [&](int slot, int tt) {
    const int kv0 = tt * 64;
    gll16(kbh + (size_t)(kv0 + srow) * 64 + swz, &Ks[slot][tid * 8]);
    gll16(vbh + (size_t)srow * 1024 + kv0 + swz, &Vs[slot][tid * 8]);
  };

  const int wrow0 = q0 + wave * 16;   // wave's first q row
  bf16x8 qf[2];
#pragma unroll
  for (int kc = 0; kc < 2; kc++)
    qf[kc] = *(const bf16x8*)&qbh[(size_t)(wrow0 + r16) * 64 + kc*32 + r4*8];

  f32x4 oacc[4] = {};
  float l_i[4] = {0.f, 0.f, 0.f, 0.f};

  const int nt = 2 * qt + 2;   // kv tiles 0..2qt+1 cover kv <= q0+127

  STAGE(0, 0);
  if (nt > 1) STAGE(1, 1);

  for (int t = 0; t < nt; t++) {
    if (t + 1 < nt) asm volatile("s_waitcnt vmcnt(2)" ::: "memory");
    else            asm volatile("s_waitcnt vmcnt(0)" ::: "memory");
    __builtin_amdgcn_sched_barrier(0);
    __builtin_amdgcn_s_barrier();      // all waves' staging of slot landed
    __builtin_amdgcn_sched_barrier(0);

    const int slot = t & 1;
    const int kv0 = t * 64;
    const bool active = (kv0 <= wrow0 + 15);   // wave-uniform

    bf16x8 kf[2][4], vf[2][4];
    if (active) {
#pragma unroll
      for (int kc = 0; kc < 2; kc++)
#pragma unroll
        for (int nf = 0; nf < 4; nf++) {
          kf[kc][nf] = *(const bf16x8*)&Ks[slot][(nf*16 + r16) * 64 +
                                                (((kc*4 + r4) ^ (r16 & 7)) * 8)];
          vf[kc][nf] = *(const bf16x8*)&Vs[slot][(nf*16 + r16) * 64 +
                                                (((kc*4 + r4) ^ (r16 & 7)) * 8)];
        }
    }
    asm volatile("s_waitcnt lgkmcnt(0)" ::: "memory");
    __builtin_amdgcn_sched_barrier(0);
    __builtin_amdgcn_s_barrier();      // all waves done reading slot
    __builtin_amdgcn_sched_barrier(0);

    if (t + 2 < nt) STAGE(slot, t + 2);

    if (active) {
      f32x4 sacc[4] = {};
#pragma unroll
      for (int kc = 0; kc < 2; kc++)
#pragma unroll
        for (int nf = 0; nf < 4; nf++)
          sacc[nf] = mfma16(qf[kc], kf[kc][nf], sacc[nf]);

      const bool needmask = (kv0 + 63 > wrow0);   // wave-uniform
#pragma unroll
      for (int jj = 0; jj < 4; jj++) {
        float vv[4];
#pragma unroll
        for (int nf = 0; nf < 4; nf++) vv[nf] = sacc[nf][jj];
        if (needmask) {
          const int qrow = wrow0 + r4*4 + jj;
#pragma unroll
          for (int nf = 0; nf < 4; nf++)
            if (kv0 + nf*16 + r16 > qrow) vv[nf] = -1e30f;
        }
        float p0 = __expf(vv[0]), p1 = __expf(vv[1]);
        float p2 = __expf(vv[2]), p3 = __expf(vv[3]);
        l_i[jj] += (p0 + p1) + (p2 + p3);
        const int prow = (wave*16 + r4*4 + jj) * 72;
        Ps[prow + r16     ] = f2bf(p0);
        Ps[prow + 16 + r16] = f2bf(p1);
        Ps[prow + 32 + r16] = f2bf(p2);
        Ps[prow + 48 + r16] = f2bf(p3);
      }

#pragma unroll
      for (int kc = 0; kc < 2; kc++) {
        bf16x8 pf = *(const bf16x8*)&Ps[(wave*16 + r16) * 72 + kc*32 + r4*8];
#pragma unroll
        for (int nh = 0; nh < 4; nh++)
          oacc[nh] = mfma16(pf, vf[kc][nh], oacc[nh]);
      }
    }
    __builtin_amdgcn_sched_barrier(0);
  }

#pragma unroll
  for (int jj = 0; jj < 4; jj++)
#pragma unroll
    for (int mk = 8; mk >= 1; mk >>= 1) l_i[jj] += __shfl_xor(l_i[jj], mk);

#pragma unroll
  for (int nh = 0; nh < 4; nh++) {
#pragma unroll
    for (int jj = 0; jj < 4; jj++) {
      const int row = wrow0 + r4*4 + jj;
      const int col = nh*16 + r16;
      const float o = oacc[nh][jj] / l_i[jj];
      att[(size_t)(b * 1024 + row) * 1024 + h*64 + col] = f2bf(o);
    }
  }
}

// ---------------------------------------------------------------------------
extern "C" void kernel_launch(void* const* d_in, const int* in_sizes, int n_in,
                              void* d_out, int out_size, void* d_ws, size_t ws_size,
                              hipStream_t stream)
{
  const int*   toks    = (const int*)  d_in[0];
  const float* tok_emb = (const float*)d_in[1];
  const float* pos_emb = (const float*)d_in[2];
  const float* Wq      = (const float*)d_in[3];
  const float* Wk      = (const float*)d_in[4];
  const float* Wv      = (const float*)d_in[5];
  const float* Wo      = (const float*)d_in[6];
  const float* bo      = (const float*)d_in[7];
  const float* ln1_g   = (const float*)d_in[8];
  const float* ln1_b   = (const float*)d_in[9];
  const float* ln2_g   = (const float*)d_in[10];
  const float* ln2_b   = (const float*)d_in[11];
  const float* W1      = (const float*)d_in[12];
  const float* b1      = (const float*)d_in[13];
  const float* W2      = (const float*)d_in[14];
  const float* b2      = (const float*)d_in[15];
  const float* lnf_g   = (const float*)d_in[16];
  const float* lnf_b   = (const float*)d_in[17];
  const float* Wout    = (const float*)d_in[18];
  const float* bout    = (const float*)d_in[19];
  float* out = (float*)d_out;

  char* w = (char*)d_ws;
  size_t off = 0;
  auto alloc = [&](size_t bytes) -> void* {
    void* p = w + off; off += (bytes + 255) & ~(size_t)255; return p;
  };
  unsigned short* wqT   = (unsigned short*)alloc(8ull*1024*1024*2);
  unsigned short* wkT   = (unsigned short*)alloc(8ull*1024*1024*2);
  unsigned short* wvT   = (unsigned short*)alloc(8ull*1024*1024*2);
  unsigned short* woT   = (unsigned short*)alloc(8ull*1024*1024*2);
  unsigned short* w1T   = (unsigned short*)alloc(8ull*1024*4096*2);
  unsigned short* w2T   = (unsigned short*)alloc(8ull*4096*1024*2);
  unsigned short* woutT = (unsigned short*)alloc(256ull*1024*2);
  float*          x     = (float*)         alloc(4096ull*1024*4);
  unsigned short* hbuf  = (unsigned short*)alloc(4096ull*1024*2);
  unsigned short* qbuf  = (unsigned short*)alloc(64ull*1024*64*2);
  unsigned short* kbuf  = (unsigned short*)alloc(64ull*1024*64*2);
  unsigned short* vtb   = (unsigned short*)alloc(64ull*1024*64*2);
  unsigned short* att   = (unsigned short*)alloc(4096ull*1024*2);
  unsigned short* ff    = (unsigned short*)alloc(4096ull*4096*2);
  unsigned short* part16= (unsigned short*)alloc(4ull*4194304*2);   // bf16 split-K partials
  float*          part  = (float*)         alloc(8ull*1048576*4);   // f32 partials (logits)
  (void)ws_size; (void)in_sizes; (void)n_in; (void)out_size;

  dim3 tb(32, 8);
  tcvt_k<<<dim3(32, 32, 8),  tb, 0, stream>>>(Wq,   wqT,   1024, 1024);
  tcvt_k<<<dim3(32, 32, 8),  tb, 0, stream>>>(Wk,   wkT,   1024, 1024);
  tcvt_k<<<dim3(32, 32, 8),  tb, 0, stream>>>(Wv,   wvT,   1024, 1024);
  tcvt_k<<<dim3(32, 32, 8),  tb, 0, stream>>>(Wo,   woT,   1024, 1024);
  tcvt_k<<<dim3(128, 32, 8), tb, 0, stream>>>(W1,   w1T,   1024, 4096);
  tcvt_k<<<dim3(32, 128, 8), tb, 0, stream>>>(W2,   w2T,   4096, 1024);
  tcvt_k<<<dim3(8, 32, 1),   tb, 0, stream>>>(Wout, woutT, 1024, 256);

  // embed + layer-0 LN1 fused
  embed_ln_k<<<4096, 256, 0, stream>>>(toks, tok_emb, pos_emb,
                                       ln1_g, ln1_b, x, hbuf);

  for (int l = 0; l < 8; l++) {
    // QKV: 128^2 engine, 768 blocks (3/CU) — R12 config
    gemm_k<0><<<dim3(32, 8, 3), 256, 0, stream>>>(hbuf,
        wqT + (size_t)l*1048576, wkT + (size_t)l*1048576, wvT + (size_t)l*1048576,
        qbuf, kbuf, vtb, 1024, 1024, 1024, nullptr);
    // attn v2: QBLK=128, 512 blocks x 512 thr  [THE ONE CHANGE vs R12]
    attn_k<<<512, 512, 0, stream>>>(qbuf, kbuf, vtb, att);
    // Wo: 128^2 split-K x4 (Kc=256) -> bf16 partials, fused reduce+LN2
    gemm_k<5><<<dim3(32, 8, 4), 256, 0, stream>>>(att,
        woT + (size_t)l*1048576, nullptr, nullptr,
        part16, nullptr, nullptr, 1024, 1024, 256, nullptr);
    redln_k<<<4096, 256, 0, stream>>>(part16, bo + l*1024,
        ln2_g + l*1024, ln2_b + l*1024, x, hbuf);
    // FFN1: 256^2 8-phase, relu -> bf16 ff
    gemm8_k<2><<<dim3(16, 16), 512, 0, stream>>>(hbuf,
        w1T + (size_t)l*4194304, b1 + l*4096, ff, 1024, 4096, 1024);
    // FFN2: 256^2 8-phase split-K x4 (Kc=1024) -> bf16 partials
    gemm8_k<5><<<dim3(16, 4, 4), 512, 0, stream>>>(ff,
        w2T + (size_t)l*4194304, nullptr, part16, 4096, 1024, 1024);
    if (l < 7)
      redln_k<<<4096, 256, 0, stream>>>(part16, b2 + l*1024,
          ln1_g + (l+1)*1024, ln1_b + (l+1)*1024, x, hbuf);
    else
      redln_k<<<4096, 256, 0, stream>>>(part16, b2 + l*1024,
          lnf_g, lnf_b, x, hbuf);
  }

  // logits: split-K x8 (Kc=128, f32 partials), then bias-reduce into out
  gemm_k<4><<<dim3(32, 2, 8), 256, 0, stream>>>(hbuf, woutT, nullptr, nullptr,
      nullptr, nullptr, nullptr, 1024, 256, 128, part);
  red_k<<<1024, 256, 0, stream>>>(part, bout, out, 262144, 63, 8);
}

// Round 16
// 1659.026 us; speedup vs baseline: 1.1134x; 1.0719x over previous
//
#include <hip/hip_runtime.h>

#define DEV __device__ __forceinline__

typedef __bf16 bf16x8 __attribute__((ext_vector_type(8)));
typedef float  f32x4  __attribute__((ext_vector_type(4)));

typedef const __attribute__((address_space(1))) unsigned int* gas_ptr;
typedef       __attribute__((address_space(3))) unsigned int* las_ptr;

DEV unsigned short f2bf(float f) {
  union { __bf16 h; unsigned short u; } c; c.h = (__bf16)f; return c.u;
}

DEV float bf2f(unsigned short u) {
  union { unsigned int i; float f; } c; c.i = (unsigned int)u << 16; return c.f;
}

DEV void gll16(const void* g, void* l) {
  __builtin_amdgcn_global_load_lds((gas_ptr)g, (las_ptr)l, 16, 0, 0);
}

DEV f32x4 mfma16(bf16x8 a, bf16x8 b, f32x4 c) {
  return __builtin_amdgcn_mfma_f32_16x16x32_bf16(a, b, c, 0, 0, 0);
}

// ---------------------------------------------------------------------------
// Transpose + f32->bf16 convert: src [K,N] f32 -> dst [N,K] bf16. grid.z = layer.
__global__ __launch_bounds__(256)
void tcvt_k(const float* __restrict__ src, unsigned short* __restrict__ dst,
            int K, int N)
{
  __shared__ float t[32][33];
  const int tx = threadIdx.x, ty = threadIdx.y;
  const size_t mo = (size_t)blockIdx.z * K * N;
  const int n0 = blockIdx.x * 32, k0 = blockIdx.y * 32;
  const float* s = src + mo;
  unsigned short* d = dst + mo;
#pragma unroll
  for (int i = 0; i < 4; i++)
    t[ty + i*8][tx] = s[(size_t)(k0 + ty + i*8) * N + n0 + tx];
  __syncthreads();
#pragma unroll
  for (int i = 0; i < 4; i++)
    d[(size_t)(n0 + ty + i*8) * K + k0 + tx] = f2bf(t[tx][ty + i*8]);
}

// ---------------------------------------------------------------------------
// Shared LN tail
DEV void ln_tail(float4 s, const float* __restrict__ g,
                 const float* __restrict__ bta,
                 unsigned short* __restrict__ hrow, int t, float* red)
{
  float sm  = s.x + s.y + s.z + s.w;
  float sq = s.x*s.x + s.y*s.y + s.z*s.z + s.w*s.w;
#pragma unroll
  for (int mk = 32; mk >= 1; mk >>= 1) {
    sm += __shfl_xor(sm, mk);
    sq += __shfl_xor(sq, mk);
  }
  const int wv = t >> 6;
  if ((t & 63) == 0) { red[wv] = sm; red[4 + wv] = sq; }
  __syncthreads();
  sm = red[0] + red[1] + red[2] + red[3];
  sq = red[4] + red[5] + red[6] + red[7];
  const float mu = sm * (1.f/1024.f);
  const float rs = rsqrtf(sq * (1.f/1024.f) - mu*mu + 1e-5f);
  const float4 gv = ((const float4*)g)[t];
  const float4 bv = ((const float4*)bta)[t];
  ushort4 o;
  o.x = f2bf((s.x - mu) * rs * gv.x + bv.x);
  o.y = f2bf((s.y - mu) * rs * gv.y + bv.y);
  o.z = f2bf((s.z - mu) * rs * gv.z + bv.z);
  o.w = f2bf((s.w - mu) * rs * gv.w + bv.w);
  ((ushort4*)hrow)[t] = o;
}

// ---------------------------------------------------------------------------
// Embedding + LN1(layer0)
__global__ __launch_bounds__(256)
void embed_ln_k(const int* __restrict__ toks, const float* __restrict__ te,
                const float* __restrict__ pe, const float* __restrict__ g,
                const float* __restrict__ bta,
                float* __restrict__ x, unsigned short* __restrict__ h)
{
  __shared__ float red[8];
  const int row = blockIdx.x, t = threadIdx.x;
  const int tok = toks[row], s = row & 1023;
  float4 a = ((const float4*)(te + (size_t)tok * 1024))[t];
  float4 p = ((const float4*)(pe + (size_t)s   * 1024))[t];
  float4 v; v.x = a.x+p.x; v.y = a.y+p.y; v.z = a.z+p.z; v.w = a.w+p.w;
  ((float4*)(x + (size_t)row * 1024))[t] = v;
  ln_tail(v, g, bta, h + (size_t)row * 1024, t, red);
}

// ---------------------------------------------------------------------------
// Fused split-K reduce (KZ bf16 partials) + residual + bias + LayerNorm.
// One block per row: x[row] += sum(part[0..KZ-1][row]) + bias; h = LN(x).
template<int KZ>
__global__ __launch_bounds__(256)
void redln_k(const unsigned short* __restrict__ part,
             const float* __restrict__ bias,
             const float* __restrict__ g, const float* __restrict__ bta,
             float* __restrict__ x, unsigned short* __restrict__ h)
{
  __shared__ float red[8];
  const int row = blockIdx.x, t = threadIdx.x;
  const size_t pbase = (size_t)row * 1024 + t * 4;
  float a0 = 0.f, a1 = 0.f, a2 = 0.f, a3 = 0.f;
#pragma unroll
  for (int kz = 0; kz < KZ; kz++) {
    ushort4 u = *(const ushort4*)&part[(size_t)kz * 4194304 + pbase];
    a0 += bf2f(u.x); a1 += bf2f(u.y); a2 += bf2f(u.z); a3 += bf2f(u.w);
  }
  float4 xv = ((const float4*)(x + (size_t)row * 1024))[t];
  float4 bv = ((const float4*)bias)[t];
  float4 s;
  s.x = xv.x + a0 + bv.x; s.y = xv.y + a1 + bv.y;
  s.z = xv.z + a2 + bv.z; s.w = xv.w + a3 + bv.w;
  ((float4*)(x + (size_t)row * 1024))[t] = s;
  ln_tail(s, g, bta, h + (size_t)row * 1024, t, red);
}

// ---------------------------------------------------------------------------
// bf16 GEMM, m97 structure + counted-vmcnt double-buffer. (R8/R12, passing.)
// EPI: 0 = QKV scatter (z selects Wq/Wk/Wv; q scaled 0.125; v transposed)
//      4 = split-K f32 partial  5 = split-K bf16 partial (o0 + z*4194304)
template<int EPI>
__global__ __launch_bounds__(256)
void gemm_k(const unsigned short* __restrict__ A,
            const unsigned short* __restrict__ B0,
            const unsigned short* __restrict__ B1,
            const unsigned short* __restrict__ B2,
            unsigned short* __restrict__ o0,
            unsigned short* __restrict__ o1,
            unsigned short* __restrict__ o2,
            int K, int N, int Kc, float* __restrict__ part)
{
  __shared__ __align__(16) unsigned short As[2][128 * 32];
  __shared__ __align__(16) unsigned short Bs[2][128 * 32];
  const int tid = threadIdx.x;
  const int wave = tid >> 6, lane = tid & 63;
  const int wm = wave >> 1, wn = wave & 1;
  const int m0 = blockIdx.x * 128, n0 = blockIdx.y * 128;
  const int r16 = lane & 15, r4 = lane >> 4;

  const unsigned short* Bt = B0;
  if (EPI == 0) Bt = (blockIdx.z == 0) ? B0 : (blockIdx.z == 1) ? B1 : B2;
  const int koff = (EPI >= 4) ? blockIdx.z * Kc : 0;
  const int klen = (EPI >= 4) ? Kc : K;

  const unsigned short* ga = A  + (size_t)(m0 + (tid >> 2)) * K + koff + (tid & 3) * 8;
  const unsigned short* gb = Bt + (size_t)(n0 + (tid >> 2)) * K + koff + (tid & 3) * 8;
  const size_t rstep = (size_t)64 * K;
  const int lo = wave * 512;

  auto STAGE = [&](int slot, int tt) {
    const unsigned short* gaa = ga + tt * 32;
    const unsigned short* gbb = gb + tt * 32;
    gll16(gaa,         &As[slot][lo]);
    gll16(gaa + rstep, &As[slot][lo + 2048]);
    gll16(gbb,         &Bs[slot][lo]);
    gll16(gbb + rstep, &Bs[slot][lo + 2048]);
  };

  f32x4 acc[4][4] = {};
  const int NT = klen >> 5;

  STAGE(0, 0);
  if (NT > 1) STAGE(1, 1);

  for (int t = 0; t < NT; t++) {
    if (t + 1 < NT) asm volatile("s_waitcnt vmcnt(4)" ::: "memory");
    else            asm volatile("s_waitcnt vmcnt(0)" ::: "memory");
    __builtin_amdgcn_sched_barrier(0);
    __builtin_amdgcn_s_barrier();
    __builtin_amdgcn_sched_barrier(0);

    const int slot = t & 1;
    bf16x8 av[4], bv[4];
#pragma unroll
    for (int mf = 0; mf < 4; mf++)
      av[mf] = *(const bf16x8*)&As[slot][(wm*64 + mf*16 + r16) * 32 + r4 * 8];
#pragma unroll
    for (int nf = 0; nf < 4; nf++)
      bv[nf] = *(const bf16x8*)&Bs[slot][(wn*64 + nf*16 + r16) * 32 + r4 * 8];
    asm volatile("s_waitcnt lgkmcnt(0)" ::: "memory");
    __builtin_amdgcn_sched_barrier(0);
    __builtin_amdgcn_s_barrier();
    __builtin_amdgcn_sched_barrier(0);

    if (t + 2 < NT) STAGE(slot, t + 2);

#pragma unroll
    for (int mf = 0; mf < 4; mf++)
#pragma unroll
      for (int nf = 0; nf < 4; nf++)
        acc[mf][nf] = mfma16(av[mf], bv[nf], acc[mf][nf]);
    __builtin_amdgcn_sched_barrier(0);
  }

  const int row0 = m0 + wm * 64, col0 = n0 + wn * 64;
  float* po = nullptr;
  if (EPI == 4)
    po = part + (size_t)blockIdx.z * ((size_t)gridDim.x * 128 * N);
  unsigned short* po16 = nullptr;
  if (EPI == 5)
    po16 = o0 + (size_t)blockIdx.z * 4194304;
#pragma unroll
  for (int mf = 0; mf < 4; mf++) {
#pragma unroll
    for (int nf = 0; nf < 4; nf++) {
#pragma unroll
      for (int jj = 0; jj < 4; jj++) {
        const int r = row0 + mf*16 + r4*4 + jj;
        const int c = col0 + nf*16 + r16;
        const float v = acc[mf][nf][jj];
        if (EPI == 0) {
          const int z = blockIdx.z;
          const int b_ = r >> 10, s_ = r & 1023;
          const int hh = c >> 6, e = c & 63;
          if (z == 0)
            o0[((size_t)(b_*16 + hh) * 1024 + s_) * 64 + e] = f2bf(v * 0.125f);
          else if (z == 1)
            o1[((size_t)(b_*16 + hh) * 1024 + s_) * 64 + e] = f2bf(v);
          else
            o2[((size_t)(b_*16 + hh) * 64 + e) * 1024 + s_] = f2bf(v);
        } else if (EPI == 4) {
          po[(size_t)r * N + c] = v;
        } else {
          po16[(size_t)r * N + c] = f2bf(v);
        }
      }
    }
  }
}

// ---------------------------------------------------------------------------
// 256x256 8-phase GEMM (T3+T4+T5), BK=64, 512 thr / 8 waves. (R12, passing.)
// NOTE: 128KB LDS -> 1 block/CU; only use with grid >= 256 blocks (FFN1/FFN2).
// EPI: 2 = relu(acc+bias)->bf16, 5 = bf16 split-K partial (o0 + z*4194304)
template<int EPI>
__global__ __launch_bounds__(512, 2)
void gemm8_k(const unsigned short* __restrict__ A,
             const unsigned short* __restrict__ Bt,
             const float* __restrict__ bias,
             unsigned short* __restrict__ o0,
             int K, int N, int Kc)
{
  __shared__ __align__(16) unsigned short LA[2][2][8192];
  __shared__ __align__(16) unsigned short LB[2][2][8192];
  const int tid = threadIdx.x;
  const int wave = tid >> 6, lane = tid & 63;
  const int wm = wave >> 2, wn = wave & 3;
  const int r16 = lane & 15, r4 = lane >> 4;
  const int m0 = blockIdx.x * 256, n0 = blockIdx.y * 256;
  const int koff = (EPI == 5) ? blockIdx.z * Kc : 0;
  const int NT = Kc >> 6;

  const unsigned short* As0 = A  + (size_t)m0 * K + koff;
  const unsigned short* As1 = A  + (size_t)(m0 + 128) * K + koff;
  const unsigned short* Bs0 = Bt + (size_t)n0 * K + koff;
  const unsigned short* Bs1 = Bt + (size_t)(n0 + 128) * K + koff;

  auto STAGEH = [&](unsigned short* lds, const unsigned short* gsrc) {
    const int c0 = tid, r0 = c0 >> 3;
    gll16(gsrc + (size_t)r0 * K + ((c0 & 7) ^ (r0 & 7)) * 8, lds + c0 * 8);
    const int c1 = 512 + tid, r1 = c1 >> 3;
    gll16(gsrc + (size_t)r1 * K + ((c1 & 7) ^ (r1 & 7)) * 8, lds + c1 * 8);
  };

  f32x4 acc[8][4] = {};
  bf16x8 avx[4][2], bvx[2][2][2];

  STAGEH(&LB[0][0][0], Bs0);
  STAGEH(&LB[0][1][0], Bs1);
  STAGEH(&LA[0][0][0], As0);
  STAGEH(&LA[0][1][0], As1);
  if (NT > 1) {
    STAGEH(&LB[1][0][0], Bs0 + 64);
    STAGEH(&LB[1][1][0], Bs1 + 64);
  }

  for (int t = 0; t < NT; ++t) {
    const int slot = t & 1;
    if (t + 1 < NT) asm volatile("s_waitcnt vmcnt(4)" ::: "memory");
    else            asm volatile("s_waitcnt vmcnt(0)" ::: "memory");
    __builtin_amdgcn_sched_barrier(0);
    __builtin_amdgcn_s_barrier();
    __builtin_amdgcn_sched_barrier(0);

    // ---- p1: (qr0, qc0)
#pragma unroll
    for (int mfq = 0; mfq < 4; mfq++)
#pragma unroll
      for (int kk = 0; kk < 2; kk++)
        avx[mfq][kk] = *(const bf16x8*)&LA[slot][wm][
            (mfq*16 + r16) * 64 + (((kk*4 + r4) ^ (r16 & 7)) * 8)];
#pragma unroll
    for (int nfq = 0; nfq < 2; nfq++)
#pragma unroll
      for (int kk = 0; kk < 2; kk++)
        bvx[0][nfq][kk] = *(const bf16x8*)&LB[slot][wn >> 1][
            ((wn & 1)*64 + nfq*16 + r16) * 64 + (((kk*4 + r4) ^ (r16 & 7)) * 8)];
    if (t + 1 < NT) STAGEH(&LA[slot ^ 1][0][0], As0 + (t + 1) * 64);
    asm volatile("s_waitcnt lgkmcnt(0)" ::: "memory");
    __builtin_amdgcn_sched_barrier(0);
    __builtin_amdgcn_s_setprio(1);
#pragma unroll
    for (int mfq = 0; mfq < 4; mfq++)
#pragma unroll
      for (int nfq = 0; nfq < 2; nfq++)
#pragma unroll
        for (int kk = 0; kk < 2; kk++)
          acc[mfq][nfq] = mfma16(avx[mfq][kk], bvx[0][nfq][kk], acc[mfq][nfq]);
    __builtin_amdgcn_s_setprio(0);

    // ---- p2: (qr0, qc1)
#pragma unroll
    for (int nfq = 0; nfq < 2; nfq++)
#pragma unroll
      for (int kk = 0; kk < 2; kk++)
        bvx[1][nfq][kk] = *(const bf16x8*)&LB[slot][wn >> 1][
            ((wn & 1)*64 + 32 + nfq*16 + r16) * 64 + (((kk*4 + r4) ^ (r16 & 7)) * 8)];
    if (t + 1 < NT) STAGEH(&LA[slot ^ 1][1][0], As1 + (t + 1) * 64);
    asm volatile("s_waitcnt lgkmcnt(0)" ::: "memory");
    __builtin_amdgcn_sched_barrier(0);
    __builtin_amdgcn_s_setprio(1);
#pragma unroll
    for (int mfq = 0; mfq < 4; mfq++)
#pragma unroll
      for (int nfq = 0; nfq < 2; nfq++)
#pragma unroll
        for (int kk = 0; kk < 2; kk++)
          acc[mfq][2 + nfq] = mfma16(avx[mfq][kk], bvx[1][nfq][kk], acc[mfq][2 + nfq]);
    __builtin_amdgcn_s_setprio(0);

    __builtin_amdgcn_sched_barrier(0);
    __builtin_amdgcn_s_barrier();
    __builtin_amdgcn_sched_barrier(0);

    // ---- p3: (qr1, qc0)
#pragma unroll
    for (int mfq = 0; mfq < 4; mfq++)
#pragma unroll
      for (int kk = 0; kk < 2; kk++)
        avx[mfq][kk] = *(const bf16x8*)&LA[slot][wm][
            (64 + mfq*16 + r16) * 64 + (((kk*4 + r4) ^ (r16 & 7)) * 8)];
    if (t + 2 < NT) STAGEH(&LB[slot][0][0], Bs0 + (t + 2) * 64);
    asm volatile("s_waitcnt lgkmcnt(0)" ::: "memory");
    __builtin_amdgcn_sched_barrier(0);
    __builtin_amdgcn_s_setprio(1);
#pragma unroll
    for (int mfq = 0; mfq < 4; mfq++)
#pragma unroll
      for (int nfq = 0; nfq < 2; nfq++)
#pragma unroll
        for (int kk = 0; kk < 2; kk++)
          acc[4 + mfq][nfq] = mfma16(avx[mfq][kk], bvx[0][nfq][kk], acc[4 + mfq][nfq]);
    __builtin_amdgcn_s_setprio(0);

    // ---- p4: (qr1, qc1)
    if (t + 2 < NT) STAGEH(&LB[slot][1][0], Bs1 + (t + 2) * 64);
    __builtin_amdgcn_s_setprio(1);
#pragma unroll
    for (int mfq = 0; mfq < 4; mfq++)
#pragma unroll
      for (int nfq = 0; nfq < 2; nfq++)
#pragma unroll
        for (int kk = 0; kk < 2; kk++)
          acc[4 + mfq][2 + nfq] = mfma16(avx[mfq][kk], bvx[1][nfq][kk], acc[4 + mfq][2 + nfq]);
    __builtin_amdgcn_s_setprio(0);
    __builtin_amdgcn_sched_barrier(0);
  }

  // epilogue
  const int row0 = m0 + wm * 128, col0 = n0 + wn * 64;
  unsigned short* po16 = o0;
  if (EPI == 5) po16 = o0 + (size_t)blockIdx.z * 4194304;
#pragma unroll
  for (int mf = 0; mf < 8; mf++) {
#pragma unroll
    for (int nf = 0; nf < 4; nf++) {
#pragma unroll
      for (int jj = 0; jj < 4; jj++) {
        const int r = row0 + mf*16 + r4*4 + jj;
        const int c = col0 + nf*16 + r16;
        const float v = acc[mf][nf][jj];
        if (EPI == 2) {
          const float t2 = v + bias[c];
          po16[(size_t)r * N + c] = f2bf(t2 > 0.f ? t2 : 0.f);
        } else {
          po16[(size_t)r * N + c] = f2bf(v);
        }
      }
    }
  }
}

// ---------------------------------------------------------------------------
// Split-K reduce (f32 partials, logits path): outw = sum + bias.
__global__ __launch_bounds__(256)
void red_k(const float* __restrict__ part, const float* __restrict__ bias,
           float* __restrict__ outw, int n4, int nm4, int KZ)
{
  const float4* p4 = (const float4*)part;
  const float4* b4 = (const float4*)bias;
  for (size_t i = (size_t)blockIdx.x * 256 + threadIdx.x; i < (size_t)n4;
       i += (size_t)gridDim.x * 256) {
    float4 s = p4[i];
    for (int kz = 1; kz < KZ; kz++) {
      float4 t = p4[i + (size_t)kz * n4];
      s.x += t.x; s.y += t.y; s.z += t.z; s.w += t.w;
    }
    float4 bv = b4[i & nm4];
    s.x += bv.x; s.y += bv.y; s.z += bv.z; s.w += bv.w;
    ((float4*)outw)[i] = s;
  }
}

// ---------------------------------------------------------------------------
// Flash attention, counted-vmcnt pipeline + fixed-shift softmax. (R11/R12,
// passing — best measured config.) 1024 blocks x 256 thr (4 waves), QBLK=64.
__global__ __launch_bounds__(256)
void attn_k(const unsigned short* __restrict__ qb,
            const unsigned short* __restrict__ kb,
            const unsigned short* __restrict__ vtb,
            unsigned short* __restrict__ att)
{
  __shared__ __align__(16) unsigned short Ks[2][64 * 64];
  __shared__ __align__(16) unsigned short Vs[2][64 * 64];
  __shared__ __align__(16) unsigned short Ps[64 * 72];
  const int flat = blockIdx.x;
  const int job  = (flat & 7) * 128 + (flat >> 3);
  const int qt   = 15 - (job & 15);
  const int h    = (job >> 4) & 15;
  const int b    = job >> 8;
  const int tid = threadIdx.x, wave = tid >> 6, lane = tid & 63;
  const int r16 = lane & 15, r4 = lane >> 4;
  const int q0 = qt * 64;
  const size_t bh = (size_t)(b * 16 + h);
  const unsigned short* qbh = qb  + bh * 1024 * 64;
  const unsigned short* kbh = kb  + bh * 1024 * 64;
  const unsigned short* vbh = vtb + bh * 64 * 1024;

  const int swz = ((lane & 7) ^ (lane >> 3)) * 8;
  const int srow = lane >> 3;

  auto STAGE = [&](int slot, int tt) {
    const int kv0 = tt * 64;
#pragma unroll
    for (int cc = 0; cc < 2; cc++) {
      const int chunk = wave * 2 + cc;
      gll16(kbh + (size_t)(kv0 + chunk*8 + srow) * 64 + swz,   &Ks[slot][chunk * 512]);
      gll16(vbh + (size_t)(chunk*8 + srow) * 1024 + kv0 + swz, &Vs[slot][chunk * 512]);
    }
  };

  bf16x8 qf[2];
#pragma unroll
  for (int kc = 0; kc < 2; kc++)
    qf[kc] = *(const bf16x8*)&qbh[(size_t)(q0 + wave*16 + r16) * 64 + kc*32 + r4*8];

  f32x4 oacc[4] = {};
  float l_i[4] = {0.f, 0.f, 0.f, 0.f};

  const int nt = qt + 1;

  STAGE(0, 0);
  if (nt > 1) STAGE(1, 1);

  for (int t = 0; t < nt; t++) {
    if (t + 1 < nt) asm volatile("s_waitcnt vmcnt(4)" ::: "memory");
    else            asm volatile("s_waitcnt vmcnt(0)" ::: "memory");
    __builtin_amdgcn_sched_barrier(0);
    __builtin_amdgcn_s_barrier();
    __builtin_amdgcn_sched_barrier(0);

    const int slot = t & 1;
    bf16x8 kf[2][4], vf[2][4];
#pragma unroll
    for (int kc = 0; kc < 2; kc++)
#pragma unroll
      for (int nf = 0; nf < 4; nf++) {
        kf[kc][nf] = *(const bf16x8*)&Ks[slot][(nf*16 + r16) * 64 +
                                              (((kc*4 + r4) ^ (r16 & 7)) * 8)];
        vf[kc][nf] = *(const bf16x8*)&Vs[slot][(nf*16 + r16) * 64 +
                                              (((kc*4 + r4) ^ (r16 & 7)) * 8)];
      }
    asm volatile("s_waitcnt lgkmcnt(0)" ::: "memory");
    __builtin_amdgcn_sched_barrier(0);
    __builtin_amdgcn_s_barrier();
    __builtin_amdgcn_sched_barrier(0);

    if (t + 2 < nt) STAGE(slot, t + 2);

    f32x4 sacc[4] = {};
#pragma unroll
    for (int kc = 0; kc < 2; kc++)
#pragma unroll
      for (int nf = 0; nf < 4; nf++)
        sacc[nf] = mfma16(qf[kc], kf[kc][nf], sacc[nf]);

    const bool diag = (t == nt - 1);
#pragma unroll
    for (int jj = 0; jj < 4; jj++) {
      float vv[4];
#pragma unroll
      for (int nf = 0; nf < 4; nf++) vv[nf] = sacc[nf][jj];
      if (diag) {
        const int qrow_l = wave*16 + r4*4 + jj;
#pragma unroll
        for (int nf = 0; nf < 4; nf++)
          if (nf*16 + r16 > qrow_l) vv[nf] = -1e30f;
      }
      float p0 = __expf(vv[0]), p1 = __expf(vv[1]);
      float p2 = __expf(vv[2]), p3 = __expf(vv[3]);
      l_i[jj] += (p0 + p1) + (p2 + p3);
      const int prow = (wave*16 + r4*4 + jj) * 72;
      Ps[prow + r16     ] = f2bf(p0);
      Ps[prow + 16 + r16] = f2bf(p1);
      Ps[prow + 32 + r16] = f2bf(p2);
      Ps[prow + 48 + r16] = f2bf(p3);
    }

#pragma unroll
    for (int kc = 0; kc < 2; kc++) {
      bf16x8 pf = *(const bf16x8*)&Ps[(wave*16 + r16) * 72 + kc*32 + r4*8];
#pragma unroll
      for (int nh = 0; nh < 4; nh++)
        oacc[nh] = mfma16(pf, vf[kc][nh], oacc[nh]);
    }
    __builtin_amdgcn_sched_barrier(0);
  }

#pragma unroll
  for (int jj = 0; jj < 4; jj++)
#pragma unroll
    for (int mk = 8; mk >= 1; mk >>= 1) l_i[jj] += __shfl_xor(l_i[jj], mk);

#pragma unroll
  for (int nh = 0; nh < 4; nh++) {
#pragma unroll
    for (int jj = 0; jj < 4; jj++) {
      const int row = q0 + wave*16 + r4*4 + jj;
      const int col = nh*16 + r16;
      const float o = oacc[nh][jj] / l_i[jj];
      att[(size_t)(b * 1024 + row) * 1024 + h*64 + col] = f2bf(o);
    }
  }
}

// ---------------------------------------------------------------------------
extern "C" void kernel_launch(void* const* d_in, const int* in_sizes, int n_in,
                              void* d_out, int out_size, void* d_ws, size_t ws_size,
                              hipStream_t stream)
{
  const int*   toks    = (const int*)  d_in[0];
  const float* tok_emb = (const float*)d_in[1];
  const float* pos_emb = (const float*)d_in[2];
  const float* Wq      = (const float*)d_in[3];
  const float* Wk      = (const float*)d_in[4];
  const float* Wv      = (const float*)d_in[5];
  const float* Wo      = (const float*)d_in[6];
  const float* bo      = (const float*)d_in[7];
  const float* ln1_g   = (const float*)d_in[8];
  const float* ln1_b   = (const float*)d_in[9];
  const float* ln2_g   = (const float*)d_in[10];
  const float* ln2_b   = (const float*)d_in[11];
  const float* W1      = (const float*)d_in[12];
  const float* b1      = (const float*)d_in[13];
  const float* W2      = (const float*)d_in[14];
  const float* b2      = (const float*)d_in[15];
  const float* lnf_g   = (const float*)d_in[16];
  const float* lnf_b   = (const float*)d_in[17];
  const float* Wout    = (const float*)d_in[18];
  const float* bout    = (const float*)d_in[19];
  float* out = (float*)d_out;

  char* w = (char*)d_ws;
  size_t off = 0;
  auto alloc = [&](size_t bytes) -> void* {
    void* p = w + off; off += (bytes + 255) & ~(size_t)255; return p;
  };
  unsigned short* wqT   = (unsigned short*)alloc(8ull*1024*1024*2);
  unsigned short* wkT   = (unsigned short*)alloc(8ull*1024*1024*2);
  unsigned short* wvT   = (unsigned short*)alloc(8ull*1024*1024*2);
  unsigned short* woT   = (unsigned short*)alloc(8ull*1024*1024*2);
  unsigned short* w1T   = (unsigned short*)alloc(8ull*1024*4096*2);
  unsigned short* w2T   = (unsigned short*)alloc(8ull*4096*1024*2);
  unsigned short* woutT = (unsigned short*)alloc(256ull*1024*2);
  float*          x     = (float*)         alloc(4096ull*1024*4);
  unsigned short* hbuf  = (unsigned short*)alloc(4096ull*1024*2);
  unsigned short* qbuf  = (unsigned short*)alloc(64ull*1024*64*2);
  unsigned short* kbuf  = (unsigned short*)alloc(64ull*1024*64*2);
  unsigned short* vtb   = (unsigned short*)alloc(64ull*1024*64*2);
  unsigned short* att   = (unsigned short*)alloc(4096ull*1024*2);
  unsigned short* ff    = (unsigned short*)alloc(4096ull*4096*2);
  unsigned short* part16= (unsigned short*)alloc(4ull*4194304*2);   // bf16 split-K partials
  float*          part  = (float*)         alloc(8ull*1048576*4);   // f32 partials (logits)
  (void)ws_size; (void)in_sizes; (void)n_in; (void)out_size;

  dim3 tb(32, 8);
  tcvt_k<<<dim3(32, 32, 8),  tb, 0, stream>>>(Wq,   wqT,   1024, 1024);
  tcvt_k<<<dim3(32, 32, 8),  tb, 0, stream>>>(Wk,   wkT,   1024, 1024);
  tcvt_k<<<dim3(32, 32, 8),  tb, 0, stream>>>(Wv,   wvT,   1024, 1024);
  tcvt_k<<<dim3(32, 32, 8),  tb, 0, stream>>>(Wo,   woT,   1024, 1024);
  tcvt_k<<<dim3(128, 32, 8), tb, 0, stream>>>(W1,   w1T,   1024, 4096);
  tcvt_k<<<dim3(32, 128, 8), tb, 0, stream>>>(W2,   w2T,   4096, 1024);
  tcvt_k<<<dim3(8, 32, 1),   tb, 0, stream>>>(Wout, woutT, 1024, 256);

  // embed + layer-0 LN1 fused
  embed_ln_k<<<4096, 256, 0, stream>>>(toks, tok_emb, pos_emb,
                                       ln1_g, ln1_b, x, hbuf);

  for (int l = 0; l < 8; l++) {
    // QKV: 128^2 engine, 768 blocks (3/CU) — R12 config
    gemm_k<0><<<dim3(32, 8, 3), 256, 0, stream>>>(hbuf,
        wqT + (size_t)l*1048576, wkT + (size_t)l*1048576, wvT + (size_t)l*1048576,
        qbuf, kbuf, vtb, 1024, 1024, 1024, nullptr);
    // attn: R12 config (QBLK=64, 1024 blocks x 256 thr)
    attn_k<<<1024, 256, 0, stream>>>(qbuf, kbuf, vtb, att);
    // Wo: 128^2 split-K x2 (Kc=512) -> bf16 partials  [CHANGE: KZ 4 -> 2]
    gemm_k<5><<<dim3(32, 8, 2), 256, 0, stream>>>(att,
        woT + (size_t)l*1048576, nullptr, nullptr,
        part16, nullptr, nullptr, 1024, 1024, 512, nullptr);
    redln_k<2><<<4096, 256, 0, stream>>>(part16, bo + l*1024,
        ln2_g + l*1024, ln2_b + l*1024, x, hbuf);
    // FFN1: 256^2 8-phase, relu -> bf16 ff
    gemm8_k<2><<<dim3(16, 16), 512, 0, stream>>>(hbuf,
        w1T + (size_t)l*4194304, b1 + l*4096, ff, 1024, 4096, 1024);
    // FFN2: 256^2 8-phase split-K x4 (Kc=1024) -> bf16 partials
    gemm8_k<5><<<dim3(16, 4, 4), 512, 0, stream>>>(ff,
        w2T + (size_t)l*4194304, nullptr, part16, 4096, 1024, 1024);
    if (l < 7)
      redln_k<4><<<4096, 256, 0, stream>>>(part16, b2 + l*1024,
          ln1_g + (l+1)*1024, ln1_b + (l+1)*1024, x, hbuf);
    else
      redln_k<4><<<4096, 256, 0, stream>>>(part16, b2 + l*1024,
          lnf_g, lnf_b, x, hbuf);
  }

  // logits: split-K x8 (Kc=128, f32 partials), then bias-reduce into out
  gemm_k<4><<<dim3(32, 2, 8), 256, 0, stream>>>(hbuf, woutT, nullptr, nullptr,
      nullptr, nullptr, nullptr, 1024, 256, 128, part);
  red_k<<<1024, 256, 0, stream>>>(part, bout, out, 262144, 63, 8);
}